// Round 12
// baseline (184.628 us; speedup 1.0000x reference)
//
#include <hip/hip_runtime.h>

// Problem constants (fixed by the reference)
constexpr int NB  = 8;
constexpr int NC  = 64;
constexpr int NH  = 128;
constexpr int NW  = 128;
constexpr int NHW = NH * NW;          // 16384
constexpr int CHW = NC * NHW;         // 1048576
constexpr int SZ  = NB * CHW;         // 8388608 elements per tensor
constexpr int NPOS = NB * NHW;        // 131072 spatial positions
constexpr float EPS = 1e-5f;

typedef unsigned short u16;
using bf8   = __attribute__((ext_vector_type(8))) short;   // 8 bf16 = 4 VGPR
using u16x8 = __attribute__((ext_vector_type(8))) u16;
using u16x4 = __attribute__((ext_vector_type(4))) u16;
using f32x4 = __attribute__((ext_vector_type(4))) float;

static __device__ inline short f2bf(float f) {
    union { float f; unsigned int u; } v; v.f = f;
    unsigned int r = v.u + 0x7fffu + ((v.u >> 16) & 1u);   // RNE
    return (short)(r >> 16);
}
static __device__ inline float bf2f(u16 u) {
    union { unsigned int i; float f; } v; v.i = ((unsigned int)u) << 16;
    return v.f;
}

// ---------------------------------------------------------------------------
// (B,N,C) fp32 -> (B,C,H,W) bf16 transpose, LDS-tiled
__global__ void k_transpose(const float* __restrict__ x, u16* __restrict__ xn) {
    __shared__ float t[64 * 65];
    int b   = blockIdx.x >> 8;
    int hw0 = (blockIdx.x & 255) << 6;
    int tid = threadIdx.x;
    #pragma unroll
    for (int k = 0; k < 16; ++k) {
        int idx = tid + (k << 8);
        int c = idx & 63, hwl = idx >> 6;
        t[c * 65 + hwl] = x[((size_t)b * NHW + hw0 + hwl) * NC + c];
    }
    __syncthreads();
    #pragma unroll
    for (int k = 0; k < 16; ++k) {
        int idx = tid + (k << 8);
        int hwl = idx & 63, c = idx >> 6;
        xn[(size_t)(b * NC + c) * NHW + hw0 + hwl] = (u16)f2bf(t[c * 65 + hwl]);
    }
}

// ---------------------------------------------------------------------------
// Precompute fragment-ready bf16 weight tables in GLOBAL memory (L2-hot,
// shared by every block of every fc kernel -> no per-block LDS staging).
// Layout [d][c] unswizzled (global reads have no bank conflicts).
// blk 0: fc1w^T | 1: fc3w^T | 2: fc2w^T | 3: fc4w^T | 4: pcw (already [d][c])
// blk 5: (g.*w5)^T [64][128] | blk 6: PQ vectors.
__global__ void k_prew(const float* __restrict__ fc1w, const float* __restrict__ fc3w,
                       const float* __restrict__ fc2w, const float* __restrict__ fc4w,
                       const float* __restrict__ pcw,  const float* __restrict__ w5,
                       const float* __restrict__ lng,  const float* __restrict__ lnb,
                       u16* __restrict__ wT, float* __restrict__ PQ) {
    int blk = blockIdx.x, tid = threadIdx.x;
    if (blk < 5) {
        const float* src = (blk == 0) ? fc1w : (blk == 1) ? fc3w :
                           (blk == 2) ? fc2w : (blk == 3) ? fc4w : pcw;
        u16* dst = wT + blk * 4096;
        #pragma unroll
        for (int k = 0; k < 16; ++k) {
            int idx = tid + (k << 8);
            int d = idx >> 6, c = idx & 63;
            float v = (blk == 4) ? src[d * 64 + c] : src[c * 64 + d];
            dst[d * 64 + c] = (u16)f2bf(v);
        }
    } else if (blk == 5) {
        u16* dst = wT + 5 * 4096;
        #pragma unroll
        for (int k = 0; k < 32; ++k) {
            int idx = tid + (k << 8);
            int d = idx >> 7, c = idx & 127;
            dst[d * 128 + c] = (u16)f2bf(lng[c] * w5[c * 64 + d]);
        }
    } else if (tid < 64) {
        int d = tid;
        float P = 0.f, Q = 0.f;
        for (int c = 0; c < 128; ++c) {
            float wv = w5[c * 64 + d];
            P += lng[c] * wv;
            Q += lnb[c] * wv;
        }
        PQ[d] = P; PQ[64 + d] = Q;
    }
}

// ---------------------------------------------------------------------------
// DUAL channel-linear, swapped operands (A=input -> D[pos][d], u16x4 stores).
// Weights read as fragments from the global table: NO LDS, NO barriers.
// t1 = gelu(fc1(roll_h(xn,+1))), t2 = gelu(fc3(roll_w(xn,-1))).
__global__ __launch_bounds__(256) void
k_mfc2(const u16* __restrict__ xn,
       const u16* __restrict__ wA_g, const u16* __restrict__ wB_g,
       const float* __restrict__ b1, const float* __restrict__ b3,
       u16* __restrict__ t1, u16* __restrict__ t2) {
    int tid = threadIdx.x;
    int l = tid & 63, wv = tid >> 6;
    int q = l >> 4, col = l & 15;

    int p  = blockIdx.x * 64 + wv * 16 + col;
    int b  = p >> 14;
    int hw = p & (NHW - 1);
    int h  = hw >> 7, w = hw & 127;
    const u16* inb = xn + (size_t)b * CHW;

    f32x4 acc1[4], acc2[4];
    #pragma unroll
    for (int dt = 0; dt < 4; ++dt) {
        acc1[dt] = (f32x4){0.f, 0.f, 0.f, 0.f};
        acc2[dt] = (f32x4){0.f, 0.f, 0.f, 0.f};
    }
    #pragma unroll
    for (int ks = 0; ks < 2; ++ks) {
        bf8 f1, f2;
        #pragma unroll
        for (int j = 0; j < 8; ++j) {
            int c = ks * 32 + q * 8 + j;
            f1[j] = (short)inb[c * NHW + (((h - c) & 127) << 7) + w];   // roll_h +1
            f2[j] = (short)inb[c * NHW + (h << 7) + ((w + c) & 127)];   // roll_w -1
        }
        #pragma unroll
        for (int dt = 0; dt < 4; ++dt) {
            int d = dt * 16 + col;
            bf8 wa = *(const bf8*)&wA_g[d * 64 + ks * 32 + q * 8];
            bf8 wb = *(const bf8*)&wB_g[d * 64 + ks * 32 + q * 8];
            acc1[dt] = __builtin_amdgcn_mfma_f32_16x16x32_bf16(f1, wa, acc1[dt], 0, 0, 0);
            acc2[dt] = __builtin_amdgcn_mfma_f32_16x16x32_bf16(f2, wb, acc2[dt], 0, 0, 0);
        }
    }

    // D[row=pos][col=d]: lane (q,col) holds pos = q*4+r, d = dt*16+col
    int hwst = (blockIdx.x * 64 + wv * 16 + q * 4) & (NHW - 1);
    size_t ob = (size_t)b * CHW + hwst;
    #pragma unroll
    for (int dt = 0; dt < 4; ++dt) {
        int d = dt * 16 + col;
        float bb1 = b1[d], bb3 = b3[d];
        u16x4 o1v, o2v;
        #pragma unroll
        for (int r = 0; r < 4; ++r) {
            float v1 = acc1[dt][r] + bb1;
            v1 = 0.5f * v1 * (1.f + erff(v1 * 0.70710678118654752f));
            float v2 = acc2[dt][r] + bb3;
            v2 = 0.5f * v2 * (1.f + erff(v2 * 0.70710678118654752f));
            o1v[r] = (u16)f2bf(v1);
            o2v[r] = (u16)f2bf(v2);
        }
        *(u16x4*)&t1[ob + (size_t)d * NHW] = o1v;
        *(u16x4*)&t2[ob + (size_t)d * NHW] = o2v;
    }
}

// ---------------------------------------------------------------------------
// FUSED fc2 + fc4 + LayerNorm + fc5 (+xn residuals). Weights from global
// tables; LDS = xt only (17.9 KB, pad 140 -> ~2-way banks); one barrier.
__global__ __launch_bounds__(256) void
k_ffuse(const u16* __restrict__ t1, const u16* __restrict__ t2,
        const u16* __restrict__ xnb,
        const u16* __restrict__ wC_g, const u16* __restrict__ wD_g,
        const u16* __restrict__ wG_g,
        const float* __restrict__ fc2b, const float* __restrict__ fc4b,
        const float* __restrict__ PQ, const float* __restrict__ b5,
        u16* __restrict__ x1out) {
    __shared__ short xt[64 * 140];   // per-position concat(x_1,x_2) bf16

    int tid = threadIdx.x;
    int l = tid & 63, wv = tid >> 6;
    int q = l >> 4, col = l & 15;

    int p  = blockIdx.x * 64 + wv * 16 + col;
    int b  = p >> 14;
    int hw = p & (NHW - 1);
    int h  = hw >> 7, w = hw & 127;
    size_t base = (size_t)b * CHW;
    int pos = wv * 16 + col;

    // fc2 on roll_w(t1,+1), fc4 on roll_h(t2,+1); weights from global frags
    f32x4 acc1[4], acc2[4];
    #pragma unroll
    for (int dt = 0; dt < 4; ++dt) {
        acc1[dt] = (f32x4){0.f, 0.f, 0.f, 0.f};
        acc2[dt] = (f32x4){0.f, 0.f, 0.f, 0.f};
    }
    #pragma unroll
    for (int ks = 0; ks < 2; ++ks) {
        bf8 f1, f2;
        #pragma unroll
        for (int j = 0; j < 8; ++j) {
            int c = ks * 32 + q * 8 + j;
            f1[j] = (short)t1[base + c * NHW + (h << 7) + ((w - c) & 127)];
            f2[j] = (short)t2[base + c * NHW + (((h - c) & 127) << 7) + w];
        }
        #pragma unroll
        for (int dt = 0; dt < 4; ++dt) {
            int d = dt * 16 + col;
            bf8 wa = *(const bf8*)&wC_g[d * 64 + ks * 32 + q * 8];
            bf8 wb = *(const bf8*)&wD_g[d * 64 + ks * 32 + q * 8];
            acc1[dt] = __builtin_amdgcn_mfma_f32_16x16x32_bf16(wa, f1, acc1[dt], 0, 0, 0);
            acc2[dt] = __builtin_amdgcn_mfma_f32_16x16x32_bf16(wb, f2, acc2[dt], 0, 0, 0);
        }
    }

    // xn residuals for this lane's 16 (d, pos) outputs
    float xr[16];
    #pragma unroll
    for (int dt = 0; dt < 4; ++dt)
        #pragma unroll
        for (int r = 0; r < 4; ++r)
            xr[dt * 4 + r] = bf2f(xnb[base + (size_t)(dt * 16 + q * 4 + r) * NHW + hw]);

    // x_1/x_2 values, LN partial stats, write to xt (bf16)
    float s = 0.f, sq = 0.f;
    #pragma unroll
    for (int dt = 0; dt < 4; ++dt) {
        float v1[4], v2[4];
        #pragma unroll
        for (int r = 0; r < 4; ++r) {
            int d = dt * 16 + q * 4 + r;
            v1[r] = acc1[dt][r] + fc2b[d] + xr[dt * 4 + r];
            v2[r] = acc2[dt][r] + fc4b[d] + xr[dt * 4 + r];
            s += v1[r] + v2[r];
            sq += v1[r] * v1[r] + v2[r] * v2[r];
        }
        unsigned int pk0 = (unsigned int)(u16)f2bf(v1[0]) | ((unsigned int)(u16)f2bf(v1[1]) << 16);
        unsigned int pk1 = (unsigned int)(u16)f2bf(v1[2]) | ((unsigned int)(u16)f2bf(v1[3]) << 16);
        *(uint2*)&xt[pos * 140 + dt * 16 + q * 4] = make_uint2(pk0, pk1);
        unsigned int pk2 = (unsigned int)(u16)f2bf(v2[0]) | ((unsigned int)(u16)f2bf(v2[1]) << 16);
        unsigned int pk3 = (unsigned int)(u16)f2bf(v2[2]) | ((unsigned int)(u16)f2bf(v2[3]) << 16);
        *(uint2*)&xt[pos * 140 + 64 + dt * 16 + q * 4] = make_uint2(pk2, pk3);
    }
    s  += __shfl_xor(s, 16);  s += __shfl_xor(s, 32);
    sq += __shfl_xor(sq, 16); sq += __shfl_xor(sq, 32);
    float m    = s * (1.f / 128.f);
    float var  = sq * (1.f / 128.f) - m * m;
    float rstd = rsqrtf(var + EPS);
    float mr   = m * rstd;
    __syncthreads();   // cross-lane xt visibility (cheap at 17.9 KB LDS occupancy)

    // fc5 (K=128) from xt; wG fragments from global
    f32x4 acc[4];
    #pragma unroll
    for (int dt = 0; dt < 4; ++dt) acc[dt] = (f32x4){0.f, 0.f, 0.f, 0.f};
    #pragma unroll
    for (int ks = 0; ks < 4; ++ks) {
        bf8 bfr = *(bf8*)&xt[pos * 140 + ks * 32 + q * 8];
        #pragma unroll
        for (int dt = 0; dt < 4; ++dt) {
            int d = dt * 16 + col;
            bf8 afr = *(const bf8*)&wG_g[d * 128 + ks * 32 + q * 8];
            acc[dt] = __builtin_amdgcn_mfma_f32_16x16x32_bf16(afr, bfr, acc[dt], 0, 0, 0);
        }
    }

    size_t obase = base + hw;
    #pragma unroll
    for (int dt = 0; dt < 4; ++dt) {
        #pragma unroll
        for (int r = 0; r < 4; ++r) {
            int d = dt * 16 + q * 4 + r;
            float val = rstd * acc[dt][r] + PQ[64 + d] - mr * PQ[d] + b5[d] + xr[dt * 4 + r];
            x1out[obase + (size_t)d * NHW] = (u16)f2bf(val);
        }
    }
}

// ---------------------------------------------------------------------------
// MFMA pointwise conv, swapped operands, weights from global table.
// Non-BN variant: no LDS, no barriers. BN variant: 512B scl/sft + 1 barrier.
template<bool BNRELU_IN>
__global__ __launch_bounds__(256) void
k_mfc(const u16* __restrict__ in, const u16* __restrict__ wP_g,
      const float* __restrict__ psum, const float* __restrict__ psq,
      const float* __restrict__ bng, const float* __restrict__ bnb,
      u16* __restrict__ out) {
    __shared__ float scl[64], sft[64];
    int tid = threadIdx.x;
    int l = tid & 63, wv = tid >> 6;
    int q = l >> 4, col = l & 15;

    int p  = blockIdx.x * 64 + wv * 16 + col;
    int b  = p >> 14;
    int hw = p & (NHW - 1);
    const u16* inb = in + (size_t)b * CHW;

    u16 raw[2][8];
    #pragma unroll
    for (int ks = 0; ks < 2; ++ks)
        #pragma unroll
        for (int j = 0; j < 8; ++j)
            raw[ks][j] = inb[(ks * 32 + q * 8 + j) * NHW + hw];

    if (BNRELU_IN) {
        if (tid < 64) {
            float s = 0.f, qv = 0.f;
            #pragma unroll
            for (int i = 0; i < 32; ++i) {
                int bb = i >> 2, j = i & 3;
                int idx = ((bb * 64 + tid) << 2) + j;
                s += psum[idx]; qv += psq[idx];
            }
            const float inv = 1.f / (float)(NB * NHW);
            float m = s * inv;
            float var = qv * inv - m * m;
            float rs = rsqrtf(var + EPS);
            float sc = rs * bng[tid];
            scl[tid] = sc;
            sft[tid] = bnb[tid] - m * sc;
        }
        __syncthreads();
    }

    bf8 bfr[2];
    #pragma unroll
    for (int ks = 0; ks < 2; ++ks)
        #pragma unroll
        for (int j = 0; j < 8; ++j) {
            if (BNRELU_IN) {
                int c = ks * 32 + q * 8 + j;
                float v = fmaxf(bf2f(raw[ks][j]) * scl[c] + sft[c], 0.f);
                bfr[ks][j] = f2bf(v);
            } else {
                bfr[ks][j] = (short)raw[ks][j];
            }
        }

    f32x4 acc[4];
    #pragma unroll
    for (int dt = 0; dt < 4; ++dt) acc[dt] = (f32x4){0.f, 0.f, 0.f, 0.f};
    #pragma unroll
    for (int ks = 0; ks < 2; ++ks) {
        #pragma unroll
        for (int dt = 0; dt < 4; ++dt) {
            int d = dt * 16 + col;
            bf8 afr = *(const bf8*)&wP_g[d * 64 + ks * 32 + q * 8];
            acc[dt] = __builtin_amdgcn_mfma_f32_16x16x32_bf16(bfr[ks], afr, acc[dt], 0, 0, 0);
        }
    }

    int hwst = (blockIdx.x * 64 + wv * 16 + q * 4) & (NHW - 1);
    size_t ob = (size_t)b * CHW + hwst;
    #pragma unroll
    for (int dt = 0; dt < 4; ++dt) {
        int d = dt * 16 + col;
        u16x4 ov;
        #pragma unroll
        for (int r = 0; r < 4; ++r) ov[r] = (u16)f2bf(acc[dt][r]);
        *(u16x4*)&out[ob + (size_t)d * NHW] = ov;
    }
}

// ---------------------------------------------------------------------------
// Depthwise 3x3 conv, LDS-tiled, bf16 in/out. Block = 32 rows of one plane.
template<int DIL, bool HASBIAS, bool BNIN>
__global__ __launch_bounds__(256) void
k_dwlds(const u16* __restrict__ in, const float* __restrict__ wgt,
        const float* __restrict__ bias,
        const float* __restrict__ psumIn, const float* __restrict__ psqIn,
        const float* __restrict__ bng, const float* __restrict__ bnb,
        u16* __restrict__ out, float* __restrict__ psumOut, float* __restrict__ psqOut) {
    constexpr int STR = 136;                  // 4 pad | 128 | 4 pad
    __shared__ float tile[36 * STR];
    __shared__ float ss[256], sq[256];

    int blk = ((blockIdx.x & 7) << 8) | (blockIdx.x >> 3);  // XCD chunk swizzle
    int q   = blk & 3;
    int bc  = blk >> 2;
    int c   = bc & 63;
    int r0  = q * 32;
    int tid = threadIdx.x;
    const u16* ip = in + (size_t)bc * NHW;

    float scale = 0.f, shift = 0.f;
    if (BNIN) {
        float s = 0.f, qv = 0.f;
        #pragma unroll
        for (int i = 0; i < 32; ++i) {
            int bb = i >> 2, j = i & 3;
            int idx = ((bb * 64 + c) << 2) + j;
            s += psumIn[idx]; qv += psqIn[idx];
        }
        const float inv = 1.f / (float)(NB * NHW);
        float m = s * inv;
        float var = qv * inv - m * m;
        float rs = rsqrtf(var + EPS);
        scale = rs * bng[c];
        shift = bnb[c] - m * scale;
    }

    #pragma unroll 1
    for (int idx = tid; idx < 36 * 16; idx += 256) {
        int lr = idx >> 4, u = idx & 15;
        int gr = r0 - 2 + lr;
        float v[8] = {0.f, 0.f, 0.f, 0.f, 0.f, 0.f, 0.f, 0.f};
        if (gr >= 0 && gr < NH) {
            u16x8 raw = *(const u16x8*)(ip + gr * NW + u * 8);
            #pragma unroll
            for (int j = 0; j < 8; ++j) {
                float f = bf2f(raw[j]);
                if (BNIN) f = fmaxf(f * scale + shift, 0.f);
                v[j] = f;
            }
        }
        *(float4*)&tile[lr * STR + 4 + u * 8]     = make_float4(v[0], v[1], v[2], v[3]);
        *(float4*)&tile[lr * STR + 4 + u * 8 + 4] = make_float4(v[4], v[5], v[6], v[7]);
        if (u == 0)  *(float4*)&tile[lr * STR]       = make_float4(0.f, 0.f, 0.f, 0.f);
        if (u == 15) *(float4*)&tile[lr * STR + 132] = make_float4(0.f, 0.f, 0.f, 0.f);
    }
    __syncthreads();

    float wc[9];
    #pragma unroll
    for (int k = 0; k < 9; ++k) wc[k] = wgt[c * 9 + k];

    int row  = tid >> 3;
    int col0 = (tid & 7) * 16;
    float o[16];
    float bb = HASBIAS ? bias[c] : 0.f;
    #pragma unroll
    for (int j = 0; j < 16; ++j) o[j] = bb;

    #pragma unroll
    for (int i = 0; i < 3; ++i) {
        const float* rp = &tile[(row + 2 + (i - 1) * DIL) * STR + 4 + col0];
        float4 A  = *(const float4*)(rp - 4);
        float4 B0 = *(const float4*)(rp);
        float4 B1 = *(const float4*)(rp + 4);
        float4 B2 = *(const float4*)(rp + 8);
        float4 B3 = *(const float4*)(rp + 12);
        float4 Cc = *(const float4*)(rp + 16);
        float ww[24] = {A.x,A.y,A.z,A.w, B0.x,B0.y,B0.z,B0.w, B1.x,B1.y,B1.z,B1.w,
                        B2.x,B2.y,B2.z,B2.w, B3.x,B3.y,B3.z,B3.w, Cc.x,Cc.y,Cc.z,Cc.w};
        float w0 = wc[3 * i], w1 = wc[3 * i + 1], w2 = wc[3 * i + 2];
        #pragma unroll
        for (int j = 0; j < 16; ++j)
            o[j] += w0 * ww[4 + j - DIL] + w1 * ww[4 + j] + w2 * ww[4 + j + DIL];
    }

    u16* op = out + (size_t)bc * NHW + (r0 + row) * NW + col0;
    u16x8 o1, o2;
    #pragma unroll
    for (int j = 0; j < 8; ++j) { o1[j] = (u16)f2bf(o[j]); o2[j] = (u16)f2bf(o[8 + j]); }
    *(u16x8*)(op)     = o1;
    *(u16x8*)(op + 8) = o2;

    float s = 0.f, qq = 0.f;
    #pragma unroll
    for (int j = 0; j < 16; ++j) { s += o[j]; qq += o[j] * o[j]; }
    ss[tid] = s; sq[tid] = qq; __syncthreads();
    for (int off = 128; off > 0; off >>= 1) {
        if (tid < off) { ss[tid] += ss[tid + off]; sq[tid] += sq[tid + off]; }
        __syncthreads();
    }
    if (tid == 0) { psumOut[blk] = ss[0]; psqOut[blk] = sq[0]; }
}

// ---------------------------------------------------------------------------
// SE partial: s4[bc*4+q] = sum_{quarter} x2*y3 ; grid = 2048, bf16 inputs
__global__ void k_se_reduce(const u16* __restrict__ x2, const u16* __restrict__ y3,
                            float* __restrict__ s4) {
    __shared__ float ss[256];
    int q   = blockIdx.x & 3;
    int bc  = blockIdx.x >> 2;
    int tid = threadIdx.x;
    const u16* a  = x2 + (size_t)bc * NHW + q * (NHW / 4);
    const u16* b_ = y3 + (size_t)bc * NHW + q * (NHW / 4);
    float acc = 0.f;
    #pragma unroll
    for (int i = 0; i < 2; ++i) {
        u16x8 av = *(const u16x8*)(a + (tid + i * 256) * 8);
        u16x8 bv = *(const u16x8*)(b_ + (tid + i * 256) * 8);
        #pragma unroll
        for (int j = 0; j < 8; ++j) acc += bf2f(av[j]) * bf2f(bv[j]);
    }
    ss[tid] = acc; __syncthreads();
    for (int o = 128; o > 0; o >>= 1) {
        if (tid < o) ss[tid] += ss[tid + o];
        __syncthreads();
    }
    if (tid == 0) s4[blockIdx.x] = ss[0];
}

// ---------------------------------------------------------------------------
// out = 4*x2*y3*(1+e); SE-MLP folded in (block-uniform (b,c)).
__global__ void k_final8(const u16* __restrict__ x2, const u16* __restrict__ y3,
                         const float* __restrict__ s4,
                         const float* __restrict__ w1, const float* __restrict__ b1,
                         const float* __restrict__ w2, const float* __restrict__ b2,
                         float* __restrict__ out) {
    __shared__ float sh[64], e1[8], ev[1];
    int tid = threadIdx.x;
    int bc = blockIdx.x >> 3;            // block covers 2048 elems = 1/8 plane
    int b  = bc >> 6, c = bc & 63;

    if (tid < 64) {
        float sv = 0.f;
        #pragma unroll
        for (int j = 0; j < 4; ++j) sv += s4[(b * 64 + tid) * 4 + j];
        sh[tid] = sv * (4.f / (float)NHW);
    }
    __syncthreads();
    if (tid < 8) {
        float a = b1[tid];
        for (int cc = 0; cc < 64; ++cc) a += sh[cc] * w1[tid * 64 + cc];
        e1[tid] = a > 0.f ? a : 0.f;
    }
    __syncthreads();
    if (tid == 0) {
        float a = b2[c];
        #pragma unroll
        for (int j = 0; j < 8; ++j) a += e1[j] * w2[c * 8 + j];
        ev[0] = 1.f / (1.f + expf(-a));
    }
    __syncthreads();

    int t = blockIdx.x * 256 + tid;      // over SZ/8
    float f = 4.f * (1.f + ev[0]);
    u16x8 av = *(const u16x8*)(x2 + (size_t)t * 8);
    u16x8 bv = *(const u16x8*)(y3 + (size_t)t * 8);
    float4 o0, o1;
    o0.x = f * bf2f(av[0]) * bf2f(bv[0]); o0.y = f * bf2f(av[1]) * bf2f(bv[1]);
    o0.z = f * bf2f(av[2]) * bf2f(bv[2]); o0.w = f * bf2f(av[3]) * bf2f(bv[3]);
    o1.x = f * bf2f(av[4]) * bf2f(bv[4]); o1.y = f * bf2f(av[5]) * bf2f(bv[5]);
    o1.z = f * bf2f(av[6]) * bf2f(bv[6]); o1.w = f * bf2f(av[7]) * bf2f(bv[7]);
    *(float4*)(out + (size_t)t * 8)     = o0;
    *(float4*)(out + (size_t)t * 8 + 4) = o1;
}

// ---------------------------------------------------------------------------
extern "C" void kernel_launch(void* const* d_in, const int* in_sizes, int n_in,
                              void* d_out, int out_size, void* d_ws, size_t ws_size,
                              hipStream_t stream) {
    const float* x     = (const float*)d_in[0];
    const float* fc1w  = (const float*)d_in[1];
    const float* fc1b  = (const float*)d_in[2];
    const float* fc2w  = (const float*)d_in[3];
    const float* fc2b  = (const float*)d_in[4];
    const float* fc3w  = (const float*)d_in[5];
    const float* fc3b  = (const float*)d_in[6];
    const float* fc4w  = (const float*)d_in[7];
    const float* fc4b  = (const float*)d_in[8];
    const float* fc5w  = (const float*)d_in[9];
    const float* fc5b  = (const float*)d_in[10];
    const float* lng   = (const float*)d_in[11];
    const float* lnb   = (const float*)d_in[12];
    const float* pcw   = (const float*)d_in[13];
    const float* dww   = (const float*)d_in[14];
    const float* dwb   = (const float*)d_in[15];
    const float* dwbng = (const float*)d_in[16];
    const float* dwbnb = (const float*)d_in[17];
    const float* ddw   = (const float*)d_in[18];
    const float* ddbng = (const float*)d_in[19];
    const float* ddbnb = (const float*)d_in[20];
    const float* sew1  = (const float*)d_in[21];
    const float* seb1  = (const float*)d_in[22];
    const float* sew2  = (const float*)d_in[23];
    const float* seb2  = (const float*)d_in[24];

    float* out = (float*)d_out;
    u16* wsu = (u16*)d_ws;
    u16* bufA = wsu;                     // xn -> x2
    u16* bufB = wsu + (size_t)SZ;        // t1 -> d1
    u16* bufC = wsu + (size_t)2 * SZ;    // t2 -> d2
    u16* bufD = wsu + (size_t)3 * SZ;    // x1 -> y3
    float* st = (float*)(wsu + (size_t)4 * SZ);
    float* psumA = st;           // 2048
    float* psqA  = st + 2048;    // 2048
    float* psumB = st + 4096;    // 2048
    float* psqB  = st + 6144;    // 2048
    float* svec  = st + 8192;    // 2048
    float* pqv   = st + 10240;   // 128
    u16*   wT    = (u16*)(st + 10368);   // 28672 u16 weight-frag tables
    u16*   wA_g  = wT;               // fc1^T
    u16*   wB_g  = wT + 4096;        // fc3^T
    u16*   wC_g  = wT + 8192;        // fc2^T
    u16*   wD_g  = wT + 12288;       // fc4^T
    u16*   wP_g  = wT + 16384;       // pcw
    u16*   wG_g  = wT + 20480;       // (g.*w5)^T [64][128]

    dim3 blk(256);
    const float* nil = nullptr;

    // xn = transpose(x) -> bf16
    k_transpose<<<NB * (NHW / 64), blk, 0, stream>>>(x, bufA);
    // weight frag tables + PQ
    k_prew<<<7, blk, 0, stream>>>(fc1w, fc3w, fc2w, fc4w, pcw, fc5w, lng, lnb, wT, pqv);
    // t1,t2 = gelu(fc1(roll_h xn)), gelu(fc3(roll_w- xn))   [no LDS, no barrier]
    k_mfc2<<<NPOS / 64, blk, 0, stream>>>(bufA, wA_g, wB_g, fc1b, fc3b, bufB, bufC);
    // x1 = fused fc2+fc4+LN+fc5 (+xn residuals)   [xt-only LDS]
    k_ffuse<<<NPOS / 64, blk, 0, stream>>>(bufB, bufC, bufA, wC_g, wD_g, wG_g,
                                           fc2b, fc4b, pqv, fc5b, bufD);
    // x2 = pc(x1)   [no LDS, no barrier]
    k_mfc<false><<<NPOS / 64, blk, 0, stream>>>(bufD, wP_g, nil, nil, nil, nil, bufA);
    // d1 = dwconv3x3(x2, dil=1) + dw_b   [stats -> psumA]
    k_dwlds<1, true, false><<<2048, blk, 0, stream>>>(bufA, dww, dwb, nil, nil, nil, nil, bufB, psumA, psqA);
    // d2 = dwconv3x3(relu(bn1(d1)), dil=2)   [bn1 inline; stats -> psumB]
    k_dwlds<2, false, true><<<2048, blk, 0, stream>>>(bufB, ddw, nil, psumA, psqA, dwbng, dwbnb, bufC, psumB, psqB);
    // y3 = pc(relu(bn2(d2)))   [bn2 inline]
    k_mfc<true><<<NPOS / 64, blk, 0, stream>>>(bufC, wP_g, psumB, psqB, ddbng, ddbnb, bufD);
    // SE + final: out = 4*x2*y3*(1+e)
    k_se_reduce<<<NB * NC * 4, blk, 0, stream>>>(bufA, bufD, svec);
    k_final8<<<SZ / 2048, blk, 0, stream>>>(bufA, bufD, svec, sew1, seb1, sew2, seb2, out);
}

// Round 13
// 150.705 us; speedup vs baseline: 1.2251x; 1.2251x over previous
//
#include <hip/hip_runtime.h>

// Problem constants (fixed by the reference)
constexpr int NB  = 8;
constexpr int NC  = 64;
constexpr int NH  = 128;
constexpr int NW  = 128;
constexpr int NHW = NH * NW;          // 16384
constexpr int CHW = NC * NHW;         // 1048576
constexpr int SZ  = NB * CHW;         // 8388608 elements per tensor
constexpr int NPOS = NB * NHW;        // 131072 spatial positions
constexpr float EPS = 1e-5f;

typedef unsigned short u16;
using bf8   = __attribute__((ext_vector_type(8))) short;   // 8 bf16 = 4 VGPR
using u16x8 = __attribute__((ext_vector_type(8))) u16;
using u16x4 = __attribute__((ext_vector_type(4))) u16;
using f32x4 = __attribute__((ext_vector_type(4))) float;

static __device__ inline short f2bf(float f) {
    union { float f; unsigned int u; } v; v.f = f;
    unsigned int r = v.u + 0x7fffu + ((v.u >> 16) & 1u);   // RNE
    return (short)(r >> 16);
}
static __device__ inline float bf2f(u16 u) {
    union { unsigned int i; float f; } v; v.i = ((unsigned int)u) << 16;
    return v.f;
}

// ---------------------------------------------------------------------------
// (B,N,C) fp32 -> (B,C,H,W) bf16 transpose, LDS-tiled
__global__ void k_transpose(const float* __restrict__ x, u16* __restrict__ xn) {
    __shared__ float t[64 * 65];
    int b   = blockIdx.x >> 8;
    int hw0 = (blockIdx.x & 255) << 6;
    int tid = threadIdx.x;
    #pragma unroll
    for (int k = 0; k < 16; ++k) {
        int idx = tid + (k << 8);
        int c = idx & 63, hwl = idx >> 6;
        t[c * 65 + hwl] = x[((size_t)b * NHW + hw0 + hwl) * NC + c];
    }
    __syncthreads();
    #pragma unroll
    for (int k = 0; k < 16; ++k) {
        int idx = tid + (k << 8);
        int hwl = idx & 63, c = idx >> 6;
        xn[(size_t)(b * NC + c) * NHW + hw0 + hwl] = (u16)f2bf(t[c * 65 + hwl]);
    }
}

// ---------------------------------------------------------------------------
// Tiny: P[d] = sum_c g[c]*w5[c][d], Q[d] = sum_c b[c]*w5[c][d]
__global__ void k_pq(const float* __restrict__ w5, const float* __restrict__ lng,
                     const float* __restrict__ lnb, float* __restrict__ PQ) {
    int d = threadIdx.x;   // 64
    float P = 0.f, Q = 0.f;
    for (int c = 0; c < 128; ++c) {
        float wv = w5[c * 64 + d];
        P += lng[c] * wv;
        Q += lnb[c] * wv;
    }
    PQ[d] = P; PQ[64 + d] = Q;
}

// ---------------------------------------------------------------------------
// DUAL channel-linear, swapped operands (A=input -> D[pos][d], u16x4 stores).
// Per-block LDS weight staging (R9 structure), gathers in-loop, no prefetch.
// t1 = gelu(fc1(roll_h(xn,+1))), t2 = gelu(fc3(roll_w(xn,-1))).
__global__ __launch_bounds__(256) void
k_mfc2(const u16* __restrict__ xn,
       const float* __restrict__ w1, const float* __restrict__ b1,
       const float* __restrict__ w3, const float* __restrict__ b3,
       u16* __restrict__ t1, u16* __restrict__ t2) {
    __shared__ short wA[64 * 64];   // fc1w [d][c] swz
    __shared__ short wB[64 * 64];   // fc3w [d][c] swz
    int tid = threadIdx.x;
    int l = tid & 63, wv = tid >> 6;
    int q = l >> 4, col = l & 15;

    #pragma unroll
    for (int i = 0; i < 8; ++i) {
        int c0 = wv * 2 + i * 8;
        unsigned int pa = (unsigned int)(u16)f2bf(w1[c0 * 64 + l]) |
                          ((unsigned int)(u16)f2bf(w1[(c0 + 1) * 64 + l]) << 16);
        *(unsigned int*)&wA[l * 64 + (c0 ^ ((l & 7) << 3))] = pa;
        unsigned int pb = (unsigned int)(u16)f2bf(w3[c0 * 64 + l]) |
                          ((unsigned int)(u16)f2bf(w3[(c0 + 1) * 64 + l]) << 16);
        *(unsigned int*)&wB[l * 64 + (c0 ^ ((l & 7) << 3))] = pb;
    }
    __syncthreads();

    int p  = blockIdx.x * 64 + wv * 16 + col;
    int b  = p >> 14;
    int hw = p & (NHW - 1);
    int h  = hw >> 7, w = hw & 127;
    const u16* inb = xn + (size_t)b * CHW;

    f32x4 acc1[4], acc2[4];
    #pragma unroll
    for (int dt = 0; dt < 4; ++dt) {
        acc1[dt] = (f32x4){0.f, 0.f, 0.f, 0.f};
        acc2[dt] = (f32x4){0.f, 0.f, 0.f, 0.f};
    }
    #pragma unroll
    for (int ks = 0; ks < 2; ++ks) {
        bf8 f1, f2;
        #pragma unroll
        for (int j = 0; j < 8; ++j) {
            int c = ks * 32 + q * 8 + j;
            f1[j] = (short)inb[c * NHW + (((h - c) & 127) << 7) + w];   // roll_h +1
            f2[j] = (short)inb[c * NHW + (h << 7) + ((w + c) & 127)];   // roll_w -1
        }
        #pragma unroll
        for (int dt = 0; dt < 4; ++dt) {
            int d = dt * 16 + col;
            int wo = (ks * 32 + q * 8) ^ ((d & 7) << 3);
            acc1[dt] = __builtin_amdgcn_mfma_f32_16x16x32_bf16(f1, *(bf8*)&wA[d * 64 + wo], acc1[dt], 0, 0, 0);
            acc2[dt] = __builtin_amdgcn_mfma_f32_16x16x32_bf16(f2, *(bf8*)&wB[d * 64 + wo], acc2[dt], 0, 0, 0);
        }
    }

    // D[row=pos][col=d]: lane (q,col) holds pos = q*4+r for d = dt*16+col
    int hwst = (blockIdx.x * 64 + wv * 16 + q * 4) & (NHW - 1);
    size_t ob = (size_t)b * CHW + hwst;
    #pragma unroll
    for (int dt = 0; dt < 4; ++dt) {
        int d = dt * 16 + col;
        float bb1 = b1[d], bb3 = b3[d];
        u16x4 o1v, o2v;
        #pragma unroll
        for (int r = 0; r < 4; ++r) {
            float v1 = acc1[dt][r] + bb1;
            v1 = 0.5f * v1 * (1.f + erff(v1 * 0.70710678118654752f));
            float v2 = acc2[dt][r] + bb3;
            v2 = 0.5f * v2 * (1.f + erff(v2 * 0.70710678118654752f));
            o1v[r] = (u16)f2bf(v1);
            o2v[r] = (u16)f2bf(v2);
        }
        *(u16x4*)&t1[ob + (size_t)d * NHW] = o1v;
        *(u16x4*)&t2[ob + (size_t)d * NHW] = o2v;
    }
}

// ---------------------------------------------------------------------------
// FUSED fc2 + fc4 + LayerNorm + fc5 (+xn residuals). R9 structure; xt pad 140
// (conflict-free: 70-word stride -> 16 distinct banks across lanes).
__global__ __launch_bounds__(256) void
k_ffuse(const u16* __restrict__ t1, const u16* __restrict__ t2,
        const u16* __restrict__ xnb,
        const float* __restrict__ fc2w, const float* __restrict__ fc2b,
        const float* __restrict__ fc4w, const float* __restrict__ fc4b,
        const float* __restrict__ w5, const float* __restrict__ lng,
        const float* __restrict__ PQ, const float* __restrict__ b5,
        u16* __restrict__ x1out) {
    __shared__ short wA[64 * 64];    // fc2w [d][c] swz
    __shared__ short wB[64 * 64];    // fc4w [d][c] swz
    __shared__ short wG[64 * 128];   // (g.*w5)[d][c'] swz
    __shared__ short xt[64 * 140];   // per-position concat(x_1,x_2) bf16

    int tid = threadIdx.x;
    int l = tid & 63, wv = tid >> 6;
    int q = l >> 4, col = l & 15;

    #pragma unroll
    for (int i = 0; i < 8; ++i) {
        int c0 = wv * 2 + i * 8;
        unsigned int pa = (unsigned int)(u16)f2bf(fc2w[c0 * 64 + l]) |
                          ((unsigned int)(u16)f2bf(fc2w[(c0 + 1) * 64 + l]) << 16);
        *(unsigned int*)&wA[l * 64 + (c0 ^ ((l & 7) << 3))] = pa;
        unsigned int pb = (unsigned int)(u16)f2bf(fc4w[c0 * 64 + l]) |
                          ((unsigned int)(u16)f2bf(fc4w[(c0 + 1) * 64 + l]) << 16);
        *(unsigned int*)&wB[l * 64 + (c0 ^ ((l & 7) << 3))] = pb;
    }
    #pragma unroll
    for (int i = 0; i < 16; ++i) {
        int c0 = wv * 2 + i * 8;
        unsigned int pk = (unsigned int)(u16)f2bf(lng[c0] * w5[c0 * 64 + l]) |
                          ((unsigned int)(u16)f2bf(lng[c0 + 1] * w5[(c0 + 1) * 64 + l]) << 16);
        *(unsigned int*)&wG[l * 128 + (c0 ^ ((l & 7) << 3))] = pk;
    }
    __syncthreads();

    int p  = blockIdx.x * 64 + wv * 16 + col;
    int b  = p >> 14;
    int hw = p & (NHW - 1);
    int h  = hw >> 7, w = hw & 127;
    size_t base = (size_t)b * CHW;
    int pos = wv * 16 + col;

    // fc2 on roll_w(t1,+1), fc4 on roll_h(t2,+1)
    f32x4 acc1[4], acc2[4];
    #pragma unroll
    for (int dt = 0; dt < 4; ++dt) {
        acc1[dt] = (f32x4){0.f, 0.f, 0.f, 0.f};
        acc2[dt] = (f32x4){0.f, 0.f, 0.f, 0.f};
    }
    #pragma unroll
    for (int ks = 0; ks < 2; ++ks) {
        bf8 f1, f2;
        #pragma unroll
        for (int j = 0; j < 8; ++j) {
            int c = ks * 32 + q * 8 + j;
            f1[j] = (short)t1[base + c * NHW + (h << 7) + ((w - c) & 127)];
            f2[j] = (short)t2[base + c * NHW + (((h - c) & 127) << 7) + w];
        }
        #pragma unroll
        for (int dt = 0; dt < 4; ++dt) {
            int d = dt * 16 + col;
            int wo = (ks * 32 + q * 8) ^ ((d & 7) << 3);
            acc1[dt] = __builtin_amdgcn_mfma_f32_16x16x32_bf16(*(bf8*)&wA[d * 64 + wo], f1, acc1[dt], 0, 0, 0);
            acc2[dt] = __builtin_amdgcn_mfma_f32_16x16x32_bf16(*(bf8*)&wB[d * 64 + wo], f2, acc2[dt], 0, 0, 0);
        }
    }

    // xn residuals for this lane's 16 (d, pos) outputs
    float xr[16];
    #pragma unroll
    for (int dt = 0; dt < 4; ++dt)
        #pragma unroll
        for (int r = 0; r < 4; ++r)
            xr[dt * 4 + r] = bf2f(xnb[base + (size_t)(dt * 16 + q * 4 + r) * NHW + hw]);

    // x_1/x_2 values, LN partial stats, write to xt (bf16)
    float s = 0.f, sq = 0.f;
    #pragma unroll
    for (int dt = 0; dt < 4; ++dt) {
        float v1[4], v2[4];
        #pragma unroll
        for (int r = 0; r < 4; ++r) {
            int d = dt * 16 + q * 4 + r;
            v1[r] = acc1[dt][r] + fc2b[d] + xr[dt * 4 + r];
            v2[r] = acc2[dt][r] + fc4b[d] + xr[dt * 4 + r];
            s += v1[r] + v2[r];
            sq += v1[r] * v1[r] + v2[r] * v2[r];
        }
        unsigned int pk0 = (unsigned int)(u16)f2bf(v1[0]) | ((unsigned int)(u16)f2bf(v1[1]) << 16);
        unsigned int pk1 = (unsigned int)(u16)f2bf(v1[2]) | ((unsigned int)(u16)f2bf(v1[3]) << 16);
        *(uint2*)&xt[pos * 140 + dt * 16 + q * 4] = make_uint2(pk0, pk1);
        unsigned int pk2 = (unsigned int)(u16)f2bf(v2[0]) | ((unsigned int)(u16)f2bf(v2[1]) << 16);
        unsigned int pk3 = (unsigned int)(u16)f2bf(v2[2]) | ((unsigned int)(u16)f2bf(v2[3]) << 16);
        *(uint2*)&xt[pos * 140 + 64 + dt * 16 + q * 4] = make_uint2(pk2, pk3);
    }
    s  += __shfl_xor(s, 16);  s += __shfl_xor(s, 32);
    sq += __shfl_xor(sq, 16); sq += __shfl_xor(sq, 32);
    float m    = s * (1.f / 128.f);
    float var  = sq * (1.f / 128.f) - m * m;
    float rstd = rsqrtf(var + EPS);
    float mr   = m * rstd;
    __syncthreads();

    // fc5 (K=128) from xt
    f32x4 acc[4];
    #pragma unroll
    for (int dt = 0; dt < 4; ++dt) acc[dt] = (f32x4){0.f, 0.f, 0.f, 0.f};
    #pragma unroll
    for (int ks = 0; ks < 4; ++ks) {
        bf8 bfr = *(bf8*)&xt[pos * 140 + ks * 32 + q * 8];
        #pragma unroll
        for (int dt = 0; dt < 4; ++dt) {
            int d = dt * 16 + col;
            bf8 afr = *(bf8*)&wG[d * 128 + ((ks * 32 + q * 8) ^ ((d & 7) << 3))];
            acc[dt] = __builtin_amdgcn_mfma_f32_16x16x32_bf16(afr, bfr, acc[dt], 0, 0, 0);
        }
    }

    size_t obase = base + hw;
    #pragma unroll
    for (int dt = 0; dt < 4; ++dt) {
        #pragma unroll
        for (int r = 0; r < 4; ++r) {
            int d = dt * 16 + q * 4 + r;
            float val = rstd * acc[dt][r] + PQ[64 + d] - mr * PQ[d] + b5[d] + xr[dt * 4 + r];
            x1out[obase + (size_t)d * NHW] = (u16)f2bf(val);
        }
    }
}

// ---------------------------------------------------------------------------
// MFMA pointwise conv (K=64), swapped operands -> u16x4 stores.
// Per-block LDS weight staging; BNRELU_IN: BN finalize inline from partials.
template<bool BNRELU_IN>
__global__ __launch_bounds__(256) void
k_mfc(const u16* __restrict__ in, const float* __restrict__ wgt,
      const float* __restrict__ psum, const float* __restrict__ psq,
      const float* __restrict__ bng, const float* __restrict__ bnb,
      u16* __restrict__ out) {
    __shared__ short wt[64 * 64];
    __shared__ float scl[64], sft[64];
    int tid = threadIdx.x;
    int l = tid & 63, wv = tid >> 6;
    int q = l >> 4, col = l & 15;

    #pragma unroll
    for (int i = 0; i < 16; ++i) {
        int d = wv * 16 + i;
        wt[d * 64 + (l ^ ((d & 7) << 3))] = f2bf(wgt[d * 64 + l]);  // wgt is [d][c]
    }
    if (BNRELU_IN && tid < 64) {
        float s = 0.f, qv = 0.f;
        #pragma unroll
        for (int i = 0; i < 32; ++i) {
            int bb = i >> 2, j = i & 3;
            int idx = ((bb * 64 + tid) << 2) + j;
            s += psum[idx]; qv += psq[idx];
        }
        const float inv = 1.f / (float)(NB * NHW);
        float m = s * inv;
        float var = qv * inv - m * m;
        float rs = rsqrtf(var + EPS);
        float sc = rs * bng[tid];
        scl[tid] = sc;
        sft[tid] = bnb[tid] - m * sc;
    }
    __syncthreads();

    int p  = blockIdx.x * 64 + wv * 16 + col;
    int b  = p >> 14;
    int hw = p & (NHW - 1);
    const u16* inb = in + (size_t)b * CHW;

    f32x4 acc[4];
    #pragma unroll
    for (int dt = 0; dt < 4; ++dt) acc[dt] = (f32x4){0.f, 0.f, 0.f, 0.f};

    #pragma unroll
    for (int ks = 0; ks < 2; ++ks) {
        bf8 bfr;
        #pragma unroll
        for (int j = 0; j < 8; ++j) {
            int c = ks * 32 + q * 8 + j;
            u16 raw = inb[c * NHW + hw];
            if (BNRELU_IN) {
                float v = fmaxf(bf2f(raw) * scl[c] + sft[c], 0.f);
                bfr[j] = f2bf(v);
            } else {
                bfr[j] = (short)raw;
            }
        }
        #pragma unroll
        for (int dt = 0; dt < 4; ++dt) {
            int d = dt * 16 + col;
            bf8 afr = *(bf8*)&wt[d * 64 + ((ks * 32 + q * 8) ^ ((d & 7) << 3))];
            acc[dt] = __builtin_amdgcn_mfma_f32_16x16x32_bf16(bfr, afr, acc[dt], 0, 0, 0);
        }
    }

    // D[row=pos][col=d]: pos = q*4+r, d = dt*16+col
    int hwst = (blockIdx.x * 64 + wv * 16 + q * 4) & (NHW - 1);
    size_t ob = (size_t)b * CHW + hwst;
    #pragma unroll
    for (int dt = 0; dt < 4; ++dt) {
        int d = dt * 16 + col;
        u16x4 ov;
        #pragma unroll
        for (int r = 0; r < 4; ++r) ov[r] = (u16)f2bf(acc[dt][r]);
        *(u16x4*)&out[ob + (size_t)d * NHW] = ov;
    }
}

// ---------------------------------------------------------------------------
// Depthwise 3x3 conv, LDS-tiled, bf16 in/out. Block = 32 rows of one plane.
template<int DIL, bool HASBIAS, bool BNIN>
__global__ __launch_bounds__(256) void
k_dwlds(const u16* __restrict__ in, const float* __restrict__ wgt,
        const float* __restrict__ bias,
        const float* __restrict__ psumIn, const float* __restrict__ psqIn,
        const float* __restrict__ bng, const float* __restrict__ bnb,
        u16* __restrict__ out, float* __restrict__ psumOut, float* __restrict__ psqOut) {
    constexpr int STR = 136;                  // 4 pad | 128 | 4 pad
    __shared__ float tile[36 * STR];
    __shared__ float ss[256], sq[256];

    int blk = ((blockIdx.x & 7) << 8) | (blockIdx.x >> 3);  // XCD chunk swizzle
    int q   = blk & 3;
    int bc  = blk >> 2;
    int c   = bc & 63;
    int r0  = q * 32;
    int tid = threadIdx.x;
    const u16* ip = in + (size_t)bc * NHW;

    float scale = 0.f, shift = 0.f;
    if (BNIN) {
        float s = 0.f, qv = 0.f;
        #pragma unroll
        for (int i = 0; i < 32; ++i) {
            int bb = i >> 2, j = i & 3;
            int idx = ((bb * 64 + c) << 2) + j;
            s += psumIn[idx]; qv += psqIn[idx];
        }
        const float inv = 1.f / (float)(NB * NHW);
        float m = s * inv;
        float var = qv * inv - m * m;
        float rs = rsqrtf(var + EPS);
        scale = rs * bng[c];
        shift = bnb[c] - m * scale;
    }

    #pragma unroll 1
    for (int idx = tid; idx < 36 * 16; idx += 256) {
        int lr = idx >> 4, u = idx & 15;
        int gr = r0 - 2 + lr;
        float v[8] = {0.f, 0.f, 0.f, 0.f, 0.f, 0.f, 0.f, 0.f};
        if (gr >= 0 && gr < NH) {
            u16x8 raw = *(const u16x8*)(ip + gr * NW + u * 8);
            #pragma unroll
            for (int j = 0; j < 8; ++j) {
                float f = bf2f(raw[j]);
                if (BNIN) f = fmaxf(f * scale + shift, 0.f);
                v[j] = f;
            }
        }
        *(float4*)&tile[lr * STR + 4 + u * 8]     = make_float4(v[0], v[1], v[2], v[3]);
        *(float4*)&tile[lr * STR + 4 + u * 8 + 4] = make_float4(v[4], v[5], v[6], v[7]);
        if (u == 0)  *(float4*)&tile[lr * STR]       = make_float4(0.f, 0.f, 0.f, 0.f);
        if (u == 15) *(float4*)&tile[lr * STR + 132] = make_float4(0.f, 0.f, 0.f, 0.f);
    }
    __syncthreads();

    float wc[9];
    #pragma unroll
    for (int k = 0; k < 9; ++k) wc[k] = wgt[c * 9 + k];

    int row  = tid >> 3;
    int col0 = (tid & 7) * 16;
    float o[16];
    float bb = HASBIAS ? bias[c] : 0.f;
    #pragma unroll
    for (int j = 0; j < 16; ++j) o[j] = bb;

    #pragma unroll
    for (int i = 0; i < 3; ++i) {
        const float* rp = &tile[(row + 2 + (i - 1) * DIL) * STR + 4 + col0];
        float4 A  = *(const float4*)(rp - 4);
        float4 B0 = *(const float4*)(rp);
        float4 B1 = *(const float4*)(rp + 4);
        float4 B2 = *(const float4*)(rp + 8);
        float4 B3 = *(const float4*)(rp + 12);
        float4 Cc = *(const float4*)(rp + 16);
        float ww[24] = {A.x,A.y,A.z,A.w, B0.x,B0.y,B0.z,B0.w, B1.x,B1.y,B1.z,B1.w,
                        B2.x,B2.y,B2.z,B2.w, B3.x,B3.y,B3.z,B3.w, Cc.x,Cc.y,Cc.z,Cc.w};
        float w0 = wc[3 * i], w1 = wc[3 * i + 1], w2 = wc[3 * i + 2];
        #pragma unroll
        for (int j = 0; j < 16; ++j)
            o[j] += w0 * ww[4 + j - DIL] + w1 * ww[4 + j] + w2 * ww[4 + j + DIL];
    }

    u16* op = out + (size_t)bc * NHW + (r0 + row) * NW + col0;
    u16x8 o1, o2;
    #pragma unroll
    for (int j = 0; j < 8; ++j) { o1[j] = (u16)f2bf(o[j]); o2[j] = (u16)f2bf(o[8 + j]); }
    *(u16x8*)(op)     = o1;
    *(u16x8*)(op + 8) = o2;

    float s = 0.f, qq = 0.f;
    #pragma unroll
    for (int j = 0; j < 16; ++j) { s += o[j]; qq += o[j] * o[j]; }
    ss[tid] = s; sq[tid] = qq; __syncthreads();
    for (int off = 128; off > 0; off >>= 1) {
        if (tid < off) { ss[tid] += ss[tid + off]; sq[tid] += sq[tid + off]; }
        __syncthreads();
    }
    if (tid == 0) { psumOut[blk] = ss[0]; psqOut[blk] = sq[0]; }
}

// ---------------------------------------------------------------------------
// SE partial: s4[bc*4+q] = sum_{quarter} x2*y3 ; grid = 2048, bf16 inputs
__global__ void k_se_reduce(const u16* __restrict__ x2, const u16* __restrict__ y3,
                            float* __restrict__ s4) {
    __shared__ float ss[256];
    int q   = blockIdx.x & 3;
    int bc  = blockIdx.x >> 2;
    int tid = threadIdx.x;
    const u16* a  = x2 + (size_t)bc * NHW + q * (NHW / 4);
    const u16* b_ = y3 + (size_t)bc * NHW + q * (NHW / 4);
    float acc = 0.f;
    #pragma unroll
    for (int i = 0; i < 2; ++i) {
        u16x8 av = *(const u16x8*)(a + (tid + i * 256) * 8);
        u16x8 bv = *(const u16x8*)(b_ + (tid + i * 256) * 8);
        #pragma unroll
        for (int j = 0; j < 8; ++j) acc += bf2f(av[j]) * bf2f(bv[j]);
    }
    ss[tid] = acc; __syncthreads();
    for (int o = 128; o > 0; o >>= 1) {
        if (tid < o) ss[tid] += ss[tid + o];
        __syncthreads();
    }
    if (tid == 0) s4[blockIdx.x] = ss[0];
}

// ---------------------------------------------------------------------------
// out = 4*x2*y3*(1+e); SE-MLP folded in (block-uniform (b,c)).
__global__ void k_final8(const u16* __restrict__ x2, const u16* __restrict__ y3,
                         const float* __restrict__ s4,
                         const float* __restrict__ w1, const float* __restrict__ b1,
                         const float* __restrict__ w2, const float* __restrict__ b2,
                         float* __restrict__ out) {
    __shared__ float sh[64], e1[8], ev[1];
    int tid = threadIdx.x;
    int bc = blockIdx.x >> 3;            // block covers 2048 elems = 1/8 plane
    int b  = bc >> 6, c = bc & 63;

    if (tid < 64) {
        float sv = 0.f;
        #pragma unroll
        for (int j = 0; j < 4; ++j) sv += s4[(b * 64 + tid) * 4 + j];
        sh[tid] = sv * (4.f / (float)NHW);
    }
    __syncthreads();
    if (tid < 8) {
        float a = b1[tid];
        for (int cc = 0; cc < 64; ++cc) a += sh[cc] * w1[tid * 64 + cc];
        e1[tid] = a > 0.f ? a : 0.f;
    }
    __syncthreads();
    if (tid == 0) {
        float a = b2[c];
        #pragma unroll
        for (int j = 0; j < 8; ++j) a += e1[j] * w2[c * 8 + j];
        ev[0] = 1.f / (1.f + expf(-a));
    }
    __syncthreads();

    int t = blockIdx.x * 256 + tid;      // over SZ/8
    float f = 4.f * (1.f + ev[0]);
    u16x8 av = *(const u16x8*)(x2 + (size_t)t * 8);
    u16x8 bv = *(const u16x8*)(y3 + (size_t)t * 8);
    float4 o0, o1;
    o0.x = f * bf2f(av[0]) * bf2f(bv[0]); o0.y = f * bf2f(av[1]) * bf2f(bv[1]);
    o0.z = f * bf2f(av[2]) * bf2f(bv[2]); o0.w = f * bf2f(av[3]) * bf2f(bv[3]);
    o1.x = f * bf2f(av[4]) * bf2f(bv[4]); o1.y = f * bf2f(av[5]) * bf2f(bv[5]);
    o1.z = f * bf2f(av[6]) * bf2f(bv[6]); o1.w = f * bf2f(av[7]) * bf2f(bv[7]);
    *(float4*)(out + (size_t)t * 8)     = o0;
    *(float4*)(out + (size_t)t * 8 + 4) = o1;
}

// ---------------------------------------------------------------------------
extern "C" void kernel_launch(void* const* d_in, const int* in_sizes, int n_in,
                              void* d_out, int out_size, void* d_ws, size_t ws_size,
                              hipStream_t stream) {
    const float* x     = (const float*)d_in[0];
    const float* fc1w  = (const float*)d_in[1];
    const float* fc1b  = (const float*)d_in[2];
    const float* fc2w  = (const float*)d_in[3];
    const float* fc2b  = (const float*)d_in[4];
    const float* fc3w  = (const float*)d_in[5];
    const float* fc3b  = (const float*)d_in[6];
    const float* fc4w  = (const float*)d_in[7];
    const float* fc4b  = (const float*)d_in[8];
    const float* fc5w  = (const float*)d_in[9];
    const float* fc5b  = (const float*)d_in[10];
    const float* lng   = (const float*)d_in[11];
    const float* lnb   = (const float*)d_in[12];
    const float* pcw   = (const float*)d_in[13];
    const float* dww   = (const float*)d_in[14];
    const float* dwb   = (const float*)d_in[15];
    const float* dwbng = (const float*)d_in[16];
    const float* dwbnb = (const float*)d_in[17];
    const float* ddw   = (const float*)d_in[18];
    const float* ddbng = (const float*)d_in[19];
    const float* ddbnb = (const float*)d_in[20];
    const float* sew1  = (const float*)d_in[21];
    const float* seb1  = (const float*)d_in[22];
    const float* sew2  = (const float*)d_in[23];
    const float* seb2  = (const float*)d_in[24];

    float* out = (float*)d_out;
    u16* wsu = (u16*)d_ws;
    u16* bufA = wsu;                     // xn -> x2
    u16* bufB = wsu + (size_t)SZ;        // t1 -> d1
    u16* bufC = wsu + (size_t)2 * SZ;    // t2 -> d2
    u16* bufD = wsu + (size_t)3 * SZ;    // x1 -> y3
    float* st = (float*)(wsu + (size_t)4 * SZ);
    float* psumA = st;           // 2048
    float* psqA  = st + 2048;    // 2048
    float* psumB = st + 4096;    // 2048
    float* psqB  = st + 6144;    // 2048
    float* svec  = st + 8192;    // 2048
    float* pqv   = st + 10240;   // 128

    dim3 blk(256);
    const float* nil = nullptr;

    // xn = transpose(x) -> bf16
    k_transpose<<<NB * (NHW / 64), blk, 0, stream>>>(x, bufA);
    // P,Q for folded LN
    k_pq<<<1, 64, 0, stream>>>(fc5w, lng, lnb, pqv);
    // t1,t2 = gelu(fc1(roll_h xn)), gelu(fc3(roll_w- xn))  [swapped, vec stores]
    k_mfc2<<<NPOS / 64, blk, 0, stream>>>(bufA, fc1w, fc1b, fc3w, fc3b, bufB, bufC);
    // x1 = fused fc2+fc4+LN+fc5 (+xn residuals)  [R9 structure, pad 140]
    k_ffuse<<<NPOS / 64, blk, 0, stream>>>(bufB, bufC, bufA, fc2w, fc2b, fc4w, fc4b,
                                           fc5w, lng, pqv, fc5b, bufD);
    // x2 = pc(x1)  [swapped, vec stores]
    k_mfc<false><<<NPOS / 64, blk, 0, stream>>>(bufD, pcw, nil, nil, nil, nil, bufA);
    // d1 = dwconv3x3(x2, dil=1) + dw_b   [stats -> psumA]
    k_dwlds<1, true, false><<<2048, blk, 0, stream>>>(bufA, dww, dwb, nil, nil, nil, nil, bufB, psumA, psqA);
    // d2 = dwconv3x3(relu(bn1(d1)), dil=2)   [bn1 inline; stats -> psumB]
    k_dwlds<2, false, true><<<2048, blk, 0, stream>>>(bufB, ddw, nil, psumA, psqA, dwbng, dwbnb, bufC, psumB, psqB);
    // y3 = pc(relu(bn2(d2)))   [bn2 inline]
    k_mfc<true><<<NPOS / 64, blk, 0, stream>>>(bufC, pcw, psumB, psqB, ddbng, ddbnb, bufD);
    // SE + final: out = 4*x2*y3*(1+e)
    k_se_reduce<<<NB * NC * 4, blk, 0, stream>>>(bufA, bufD, svec);
    k_final8<<<SZ / 2048, blk, 0, stream>>>(bufA, bufD, svec, sew1, seb1, sew2, seb2, out);
}

// Round 14
// 141.244 us; speedup vs baseline: 1.3072x; 1.0670x over previous
//
#include <hip/hip_runtime.h>

// Problem constants (fixed by the reference)
constexpr int NB  = 8;
constexpr int NC  = 64;
constexpr int NH  = 128;
constexpr int NW  = 128;
constexpr int NHW = NH * NW;          // 16384
constexpr int CHW = NC * NHW;         // 1048576
constexpr int SZ  = NB * CHW;         // 8388608 elements per tensor
constexpr int NPOS = NB * NHW;        // 131072 spatial positions
constexpr float EPS = 1e-5f;

typedef unsigned short u16;
using bf8   = __attribute__((ext_vector_type(8))) short;   // 8 bf16 = 4 VGPR
using u16x8 = __attribute__((ext_vector_type(8))) u16;
using u16x4 = __attribute__((ext_vector_type(4))) u16;
using f32x4 = __attribute__((ext_vector_type(4))) float;

static __device__ inline short f2bf(float f) {
    union { float f; unsigned int u; } v; v.f = f;
    unsigned int r = v.u + 0x7fffu + ((v.u >> 16) & 1u);   // RNE
    return (short)(r >> 16);
}
static __device__ inline float bf2f(u16 u) {
    union { unsigned int i; float f; } v; v.i = ((unsigned int)u) << 16;
    return v.f;
}

// ---------------------------------------------------------------------------
// (B,N,C) fp32 -> (B,C,H,W) bf16 transpose, LDS-tiled
__global__ void k_transpose(const float* __restrict__ x, u16* __restrict__ xn) {
    __shared__ float t[64 * 65];
    int b   = blockIdx.x >> 8;
    int hw0 = (blockIdx.x & 255) << 6;
    int tid = threadIdx.x;
    #pragma unroll
    for (int k = 0; k < 16; ++k) {
        int idx = tid + (k << 8);
        int c = idx & 63, hwl = idx >> 6;
        t[c * 65 + hwl] = x[((size_t)b * NHW + hw0 + hwl) * NC + c];
    }
    __syncthreads();
    #pragma unroll
    for (int k = 0; k < 16; ++k) {
        int idx = tid + (k << 8);
        int hwl = idx & 63, c = idx >> 6;
        xn[(size_t)(b * NC + c) * NHW + hw0 + hwl] = (u16)f2bf(t[c * 65 + hwl]);
    }
}

// ---------------------------------------------------------------------------
// Tiny: P[d] = sum_c g[c]*w5[c][d], Q[d] = sum_c b[c]*w5[c][d]
__global__ void k_pq(const float* __restrict__ w5, const float* __restrict__ lng,
                     const float* __restrict__ lnb, float* __restrict__ PQ) {
    int d = threadIdx.x;   // 64
    float P = 0.f, Q = 0.f;
    for (int c = 0; c < 128; ++c) {
        float wv = w5[c * 64 + d];
        P += lng[c] * wv;
        Q += lnb[c] * wv;
    }
    PQ[d] = P; PQ[64 + d] = Q;
}

// ---------------------------------------------------------------------------
// DUAL channel-linear, swapped operands (D[pos][d], u16x4 stores).
// 512 threads = 8 waves = 128 positions/block; staging split across waves
// (waves 0-3 stage wA, 4-7 stage wB) -> half the staging work, 2x amortized.
__global__ __launch_bounds__(512) void
k_mfc2(const u16* __restrict__ xn,
       const float* __restrict__ w1, const float* __restrict__ b1,
       const float* __restrict__ w3, const float* __restrict__ b3,
       u16* __restrict__ t1, u16* __restrict__ t2) {
    __shared__ short wA[64 * 64];   // fc1w [d][c] swz
    __shared__ short wB[64 * 64];   // fc3w [d][c] swz
    int tid = threadIdx.x;
    int l = tid & 63, wv = tid >> 6;    // wv 0..7
    int q = l >> 4, col = l & 15;

    {
        const float* wsrc = (wv < 4) ? w1 : w3;
        short* wdst = (wv < 4) ? wA : wB;
        int wv4 = wv & 3;
        #pragma unroll
        for (int i = 0; i < 8; ++i) {
            int c0 = wv4 * 2 + i * 8;
            unsigned int pk = (unsigned int)(u16)f2bf(wsrc[c0 * 64 + l]) |
                              ((unsigned int)(u16)f2bf(wsrc[(c0 + 1) * 64 + l]) << 16);
            *(unsigned int*)&wdst[l * 64 + (c0 ^ ((l & 7) << 3))] = pk;
        }
    }
    __syncthreads();

    int p  = blockIdx.x * 128 + wv * 16 + col;
    int b  = p >> 14;
    int hw = p & (NHW - 1);
    int h  = hw >> 7, w = hw & 127;
    const u16* inb = xn + (size_t)b * CHW;

    f32x4 acc1[4], acc2[4];
    #pragma unroll
    for (int dt = 0; dt < 4; ++dt) {
        acc1[dt] = (f32x4){0.f, 0.f, 0.f, 0.f};
        acc2[dt] = (f32x4){0.f, 0.f, 0.f, 0.f};
    }
    #pragma unroll
    for (int ks = 0; ks < 2; ++ks) {
        bf8 f1, f2;
        #pragma unroll
        for (int j = 0; j < 8; ++j) {
            int c = ks * 32 + q * 8 + j;
            f1[j] = (short)inb[c * NHW + (((h - c) & 127) << 7) + w];   // roll_h +1
            f2[j] = (short)inb[c * NHW + (h << 7) + ((w + c) & 127)];   // roll_w -1
        }
        #pragma unroll
        for (int dt = 0; dt < 4; ++dt) {
            int d = dt * 16 + col;
            int wo = (ks * 32 + q * 8) ^ ((d & 7) << 3);
            acc1[dt] = __builtin_amdgcn_mfma_f32_16x16x32_bf16(f1, *(bf8*)&wA[d * 64 + wo], acc1[dt], 0, 0, 0);
            acc2[dt] = __builtin_amdgcn_mfma_f32_16x16x32_bf16(f2, *(bf8*)&wB[d * 64 + wo], acc2[dt], 0, 0, 0);
        }
    }

    // D[row=pos][col=d]: lane (q,col) holds pos = q*4+r for d = dt*16+col
    int hwst = (blockIdx.x * 128 + wv * 16 + q * 4) & (NHW - 1);
    size_t ob = (size_t)b * CHW + hwst;
    #pragma unroll
    for (int dt = 0; dt < 4; ++dt) {
        int d = dt * 16 + col;
        float bb1 = b1[d], bb3 = b3[d];
        u16x4 o1v, o2v;
        #pragma unroll
        for (int r = 0; r < 4; ++r) {
            float v1 = acc1[dt][r] + bb1;
            v1 = 0.5f * v1 * (1.f + erff(v1 * 0.70710678118654752f));
            float v2 = acc2[dt][r] + bb3;
            v2 = 0.5f * v2 * (1.f + erff(v2 * 0.70710678118654752f));
            o1v[r] = (u16)f2bf(v1);
            o2v[r] = (u16)f2bf(v2);
        }
        *(u16x4*)&t1[ob + (size_t)d * NHW] = o1v;
        *(u16x4*)&t2[ob + (size_t)d * NHW] = o2v;
    }
}

// ---------------------------------------------------------------------------
// FUSED fc2 + fc4 + LayerNorm + fc5 (+xn residuals). 512 threads = 128 pos.
// LDS 68.6 KB -> 2 blocks/CU = 16 waves (50% occ ceiling vs 37.5%).
__global__ __launch_bounds__(512) void
k_ffuse(const u16* __restrict__ t1, const u16* __restrict__ t2,
        const u16* __restrict__ xnb,
        const float* __restrict__ fc2w, const float* __restrict__ fc2b,
        const float* __restrict__ fc4w, const float* __restrict__ fc4b,
        const float* __restrict__ w5, const float* __restrict__ lng,
        const float* __restrict__ PQ, const float* __restrict__ b5,
        u16* __restrict__ x1out) {
    __shared__ short wA[64 * 64];     // fc2w [d][c] swz
    __shared__ short wB[64 * 64];     // fc4w [d][c] swz
    __shared__ short wG[64 * 128];    // (g.*w5)[d][c'] swz
    __shared__ short xt[128 * 140];   // per-position concat(x_1,x_2) bf16

    int tid = threadIdx.x;
    int l = tid & 63, wv = tid >> 6;   // wv 0..7
    int q = l >> 4, col = l & 15;

    {
        const float* wsrc = (wv < 4) ? fc2w : fc4w;
        short* wdst = (wv < 4) ? wA : wB;
        int wv4 = wv & 3;
        #pragma unroll
        for (int i = 0; i < 8; ++i) {
            int c0 = wv4 * 2 + i * 8;
            unsigned int pk = (unsigned int)(u16)f2bf(wsrc[c0 * 64 + l]) |
                              ((unsigned int)(u16)f2bf(wsrc[(c0 + 1) * 64 + l]) << 16);
            *(unsigned int*)&wdst[l * 64 + (c0 ^ ((l & 7) << 3))] = pk;
        }
    }
    #pragma unroll
    for (int i = 0; i < 8; ++i) {
        int c0 = wv * 2 + i * 16;      // 8 waves x 8 iters cover even 0..126
        unsigned int pk = (unsigned int)(u16)f2bf(lng[c0] * w5[c0 * 64 + l]) |
                          ((unsigned int)(u16)f2bf(lng[c0 + 1] * w5[(c0 + 1) * 64 + l]) << 16);
        *(unsigned int*)&wG[l * 128 + (c0 ^ ((l & 7) << 3))] = pk;
    }
    __syncthreads();

    int p  = blockIdx.x * 128 + wv * 16 + col;
    int b  = p >> 14;
    int hw = p & (NHW - 1);
    int h  = hw >> 7, w = hw & 127;
    size_t base = (size_t)b * CHW;
    int pos = wv * 16 + col;           // 0..127

    // fc2 on roll_w(t1,+1), fc4 on roll_h(t2,+1)
    f32x4 acc1[4], acc2[4];
    #pragma unroll
    for (int dt = 0; dt < 4; ++dt) {
        acc1[dt] = (f32x4){0.f, 0.f, 0.f, 0.f};
        acc2[dt] = (f32x4){0.f, 0.f, 0.f, 0.f};
    }
    #pragma unroll
    for (int ks = 0; ks < 2; ++ks) {
        bf8 f1, f2;
        #pragma unroll
        for (int j = 0; j < 8; ++j) {
            int c = ks * 32 + q * 8 + j;
            f1[j] = (short)t1[base + c * NHW + (h << 7) + ((w - c) & 127)];
            f2[j] = (short)t2[base + c * NHW + (((h - c) & 127) << 7) + w];
        }
        #pragma unroll
        for (int dt = 0; dt < 4; ++dt) {
            int d = dt * 16 + col;
            int wo = (ks * 32 + q * 8) ^ ((d & 7) << 3);
            acc1[dt] = __builtin_amdgcn_mfma_f32_16x16x32_bf16(*(bf8*)&wA[d * 64 + wo], f1, acc1[dt], 0, 0, 0);
            acc2[dt] = __builtin_amdgcn_mfma_f32_16x16x32_bf16(*(bf8*)&wB[d * 64 + wo], f2, acc2[dt], 0, 0, 0);
        }
    }

    // xn residuals for this lane's 16 (d, pos) outputs
    float xr[16];
    #pragma unroll
    for (int dt = 0; dt < 4; ++dt)
        #pragma unroll
        for (int r = 0; r < 4; ++r)
            xr[dt * 4 + r] = bf2f(xnb[base + (size_t)(dt * 16 + q * 4 + r) * NHW + hw]);

    // x_1/x_2 values, LN partial stats, write to xt (bf16)
    float s = 0.f, sq = 0.f;
    #pragma unroll
    for (int dt = 0; dt < 4; ++dt) {
        float v1[4], v2[4];
        #pragma unroll
        for (int r = 0; r < 4; ++r) {
            int d = dt * 16 + q * 4 + r;
            v1[r] = acc1[dt][r] + fc2b[d] + xr[dt * 4 + r];
            v2[r] = acc2[dt][r] + fc4b[d] + xr[dt * 4 + r];
            s += v1[r] + v2[r];
            sq += v1[r] * v1[r] + v2[r] * v2[r];
        }
        unsigned int pk0 = (unsigned int)(u16)f2bf(v1[0]) | ((unsigned int)(u16)f2bf(v1[1]) << 16);
        unsigned int pk1 = (unsigned int)(u16)f2bf(v1[2]) | ((unsigned int)(u16)f2bf(v1[3]) << 16);
        *(uint2*)&xt[pos * 140 + dt * 16 + q * 4] = make_uint2(pk0, pk1);
        unsigned int pk2 = (unsigned int)(u16)f2bf(v2[0]) | ((unsigned int)(u16)f2bf(v2[1]) << 16);
        unsigned int pk3 = (unsigned int)(u16)f2bf(v2[2]) | ((unsigned int)(u16)f2bf(v2[3]) << 16);
        *(uint2*)&xt[pos * 140 + 64 + dt * 16 + q * 4] = make_uint2(pk2, pk3);
    }
    s  += __shfl_xor(s, 16);  s += __shfl_xor(s, 32);
    sq += __shfl_xor(sq, 16); sq += __shfl_xor(sq, 32);
    float m    = s * (1.f / 128.f);
    float var  = sq * (1.f / 128.f) - m * m;
    float rstd = rsqrtf(var + EPS);
    float mr   = m * rstd;
    __syncthreads();

    // fc5 (K=128) from xt
    f32x4 acc[4];
    #pragma unroll
    for (int dt = 0; dt < 4; ++dt) acc[dt] = (f32x4){0.f, 0.f, 0.f, 0.f};
    #pragma unroll
    for (int ks = 0; ks < 4; ++ks) {
        bf8 bfr = *(bf8*)&xt[pos * 140 + ks * 32 + q * 8];
        #pragma unroll
        for (int dt = 0; dt < 4; ++dt) {
            int d = dt * 16 + col;
            bf8 afr = *(bf8*)&wG[d * 128 + ((ks * 32 + q * 8) ^ ((d & 7) << 3))];
            acc[dt] = __builtin_amdgcn_mfma_f32_16x16x32_bf16(afr, bfr, acc[dt], 0, 0, 0);
        }
    }

    size_t obase = base + hw;
    #pragma unroll
    for (int dt = 0; dt < 4; ++dt) {
        #pragma unroll
        for (int r = 0; r < 4; ++r) {
            int d = dt * 16 + q * 4 + r;
            float val = rstd * acc[dt][r] + PQ[64 + d] - mr * PQ[d] + b5[d] + xr[dt * 4 + r];
            x1out[obase + (size_t)d * NHW] = (u16)f2bf(val);
        }
    }
}

// ---------------------------------------------------------------------------
// MFMA pointwise conv (K=64), swapped operands -> u16x4 stores. 512 threads.
template<bool BNRELU_IN>
__global__ __launch_bounds__(512) void
k_mfc(const u16* __restrict__ in, const float* __restrict__ wgt,
      const float* __restrict__ psum, const float* __restrict__ psq,
      const float* __restrict__ bng, const float* __restrict__ bnb,
      u16* __restrict__ out) {
    __shared__ short wt[64 * 64];
    __shared__ float scl[64], sft[64];
    int tid = threadIdx.x;
    int l = tid & 63, wv = tid >> 6;   // wv 0..7
    int q = l >> 4, col = l & 15;

    #pragma unroll
    for (int i = 0; i < 8; ++i) {
        int d = wv * 8 + i;
        wt[d * 64 + (l ^ ((d & 7) << 3))] = f2bf(wgt[d * 64 + l]);  // wgt is [d][c]
    }
    if (BNRELU_IN && tid < 64) {
        float s = 0.f, qv = 0.f;
        #pragma unroll
        for (int i = 0; i < 32; ++i) {
            int bb = i >> 2, j = i & 3;
            int idx = ((bb * 64 + tid) << 2) + j;
            s += psum[idx]; qv += psq[idx];
        }
        const float inv = 1.f / (float)(NB * NHW);
        float m = s * inv;
        float var = qv * inv - m * m;
        float rs = rsqrtf(var + EPS);
        float sc = rs * bng[tid];
        scl[tid] = sc;
        sft[tid] = bnb[tid] - m * sc;
    }
    __syncthreads();

    int p  = blockIdx.x * 128 + wv * 16 + col;
    int b  = p >> 14;
    int hw = p & (NHW - 1);
    const u16* inb = in + (size_t)b * CHW;

    f32x4 acc[4];
    #pragma unroll
    for (int dt = 0; dt < 4; ++dt) acc[dt] = (f32x4){0.f, 0.f, 0.f, 0.f};

    #pragma unroll
    for (int ks = 0; ks < 2; ++ks) {
        bf8 bfr;
        #pragma unroll
        for (int j = 0; j < 8; ++j) {
            int c = ks * 32 + q * 8 + j;
            u16 raw = inb[c * NHW + hw];
            if (BNRELU_IN) {
                float v = fmaxf(bf2f(raw) * scl[c] + sft[c], 0.f);
                bfr[j] = f2bf(v);
            } else {
                bfr[j] = (short)raw;
            }
        }
        #pragma unroll
        for (int dt = 0; dt < 4; ++dt) {
            int d = dt * 16 + col;
            bf8 afr = *(bf8*)&wt[d * 64 + ((ks * 32 + q * 8) ^ ((d & 7) << 3))];
            acc[dt] = __builtin_amdgcn_mfma_f32_16x16x32_bf16(bfr, afr, acc[dt], 0, 0, 0);
        }
    }

    // D[row=pos][col=d]: pos = q*4+r, d = dt*16+col
    int hwst = (blockIdx.x * 128 + wv * 16 + q * 4) & (NHW - 1);
    size_t ob = (size_t)b * CHW + hwst;
    #pragma unroll
    for (int dt = 0; dt < 4; ++dt) {
        int d = dt * 16 + col;
        u16x4 ov;
        #pragma unroll
        for (int r = 0; r < 4; ++r) ov[r] = (u16)f2bf(acc[dt][r]);
        *(u16x4*)&out[ob + (size_t)d * NHW] = ov;
    }
}

// ---------------------------------------------------------------------------
// Depthwise 3x3 conv, LDS-tiled, bf16 in/out. Block = 32 rows of one plane.
template<int DIL, bool HASBIAS, bool BNIN>
__global__ __launch_bounds__(256) void
k_dwlds(const u16* __restrict__ in, const float* __restrict__ wgt,
        const float* __restrict__ bias,
        const float* __restrict__ psumIn, const float* __restrict__ psqIn,
        const float* __restrict__ bng, const float* __restrict__ bnb,
        u16* __restrict__ out, float* __restrict__ psumOut, float* __restrict__ psqOut) {
    constexpr int STR = 136;                  // 4 pad | 128 | 4 pad
    __shared__ float tile[36 * STR];
    __shared__ float ss[256], sq[256];

    int blk = ((blockIdx.x & 7) << 8) | (blockIdx.x >> 3);  // XCD chunk swizzle
    int q   = blk & 3;
    int bc  = blk >> 2;
    int c   = bc & 63;
    int r0  = q * 32;
    int tid = threadIdx.x;
    const u16* ip = in + (size_t)bc * NHW;

    float scale = 0.f, shift = 0.f;
    if (BNIN) {
        float s = 0.f, qv = 0.f;
        #pragma unroll
        for (int i = 0; i < 32; ++i) {
            int bb = i >> 2, j = i & 3;
            int idx = ((bb * 64 + c) << 2) + j;
            s += psumIn[idx]; qv += psqIn[idx];
        }
        const float inv = 1.f / (float)(NB * NHW);
        float m = s * inv;
        float var = qv * inv - m * m;
        float rs = rsqrtf(var + EPS);
        scale = rs * bng[c];
        shift = bnb[c] - m * scale;
    }

    #pragma unroll 1
    for (int idx = tid; idx < 36 * 16; idx += 256) {
        int lr = idx >> 4, u = idx & 15;
        int gr = r0 - 2 + lr;
        float v[8] = {0.f, 0.f, 0.f, 0.f, 0.f, 0.f, 0.f, 0.f};
        if (gr >= 0 && gr < NH) {
            u16x8 raw = *(const u16x8*)(ip + gr * NW + u * 8);
            #pragma unroll
            for (int j = 0; j < 8; ++j) {
                float f = bf2f(raw[j]);
                if (BNIN) f = fmaxf(f * scale + shift, 0.f);
                v[j] = f;
            }
        }
        *(float4*)&tile[lr * STR + 4 + u * 8]     = make_float4(v[0], v[1], v[2], v[3]);
        *(float4*)&tile[lr * STR + 4 + u * 8 + 4] = make_float4(v[4], v[5], v[6], v[7]);
        if (u == 0)  *(float4*)&tile[lr * STR]       = make_float4(0.f, 0.f, 0.f, 0.f);
        if (u == 15) *(float4*)&tile[lr * STR + 132] = make_float4(0.f, 0.f, 0.f, 0.f);
    }
    __syncthreads();

    float wc[9];
    #pragma unroll
    for (int k = 0; k < 9; ++k) wc[k] = wgt[c * 9 + k];

    int row  = tid >> 3;
    int col0 = (tid & 7) * 16;
    float o[16];
    float bb = HASBIAS ? bias[c] : 0.f;
    #pragma unroll
    for (int j = 0; j < 16; ++j) o[j] = bb;

    #pragma unroll
    for (int i = 0; i < 3; ++i) {
        const float* rp = &tile[(row + 2 + (i - 1) * DIL) * STR + 4 + col0];
        float4 A  = *(const float4*)(rp - 4);
        float4 B0 = *(const float4*)(rp);
        float4 B1 = *(const float4*)(rp + 4);
        float4 B2 = *(const float4*)(rp + 8);
        float4 B3 = *(const float4*)(rp + 12);
        float4 Cc = *(const float4*)(rp + 16);
        float ww[24] = {A.x,A.y,A.z,A.w, B0.x,B0.y,B0.z,B0.w, B1.x,B1.y,B1.z,B1.w,
                        B2.x,B2.y,B2.z,B2.w, B3.x,B3.y,B3.z,B3.w, Cc.x,Cc.y,Cc.z,Cc.w};
        float w0 = wc[3 * i], w1 = wc[3 * i + 1], w2 = wc[3 * i + 2];
        #pragma unroll
        for (int j = 0; j < 16; ++j)
            o[j] += w0 * ww[4 + j - DIL] + w1 * ww[4 + j] + w2 * ww[4 + j + DIL];
    }

    u16* op = out + (size_t)bc * NHW + (r0 + row) * NW + col0;
    u16x8 o1, o2;
    #pragma unroll
    for (int j = 0; j < 8; ++j) { o1[j] = (u16)f2bf(o[j]); o2[j] = (u16)f2bf(o[8 + j]); }
    *(u16x8*)(op)     = o1;
    *(u16x8*)(op + 8) = o2;

    float s = 0.f, qq = 0.f;
    #pragma unroll
    for (int j = 0; j < 16; ++j) { s += o[j]; qq += o[j] * o[j]; }
    ss[tid] = s; sq[tid] = qq; __syncthreads();
    for (int off = 128; off > 0; off >>= 1) {
        if (tid < off) { ss[tid] += ss[tid + off]; sq[tid] += sq[tid + off]; }
        __syncthreads();
    }
    if (tid == 0) { psumOut[blk] = ss[0]; psqOut[blk] = sq[0]; }
}

// ---------------------------------------------------------------------------
// SE partial: s4[bc*4+q] = sum_{quarter} x2*y3 ; grid = 2048, bf16 inputs
__global__ void k_se_reduce(const u16* __restrict__ x2, const u16* __restrict__ y3,
                            float* __restrict__ s4) {
    __shared__ float ss[256];
    int q   = blockIdx.x & 3;
    int bc  = blockIdx.x >> 2;
    int tid = threadIdx.x;
    const u16* a  = x2 + (size_t)bc * NHW + q * (NHW / 4);
    const u16* b_ = y3 + (size_t)bc * NHW + q * (NHW / 4);
    float acc = 0.f;
    #pragma unroll
    for (int i = 0; i < 2; ++i) {
        u16x8 av = *(const u16x8*)(a + (tid + i * 256) * 8);
        u16x8 bv = *(const u16x8*)(b_ + (tid + i * 256) * 8);
        #pragma unroll
        for (int j = 0; j < 8; ++j) acc += bf2f(av[j]) * bf2f(bv[j]);
    }
    ss[tid] = acc; __syncthreads();
    for (int o = 128; o > 0; o >>= 1) {
        if (tid < o) ss[tid] += ss[tid + o];
        __syncthreads();
    }
    if (tid == 0) s4[blockIdx.x] = ss[0];
}

// ---------------------------------------------------------------------------
// out = 4*x2*y3*(1+e); SE-MLP folded in (block-uniform (b,c)).
__global__ void k_final8(const u16* __restrict__ x2, const u16* __restrict__ y3,
                         const float* __restrict__ s4,
                         const float* __restrict__ w1, const float* __restrict__ b1,
                         const float* __restrict__ w2, const float* __restrict__ b2,
                         float* __restrict__ out) {
    __shared__ float sh[64], e1[8], ev[1];
    int tid = threadIdx.x;
    int bc = blockIdx.x >> 3;            // block covers 2048 elems = 1/8 plane
    int b  = bc >> 6, c = bc & 63;

    if (tid < 64) {
        float sv = 0.f;
        #pragma unroll
        for (int j = 0; j < 4; ++j) sv += s4[(b * 64 + tid) * 4 + j];
        sh[tid] = sv * (4.f / (float)NHW);
    }
    __syncthreads();
    if (tid < 8) {
        float a = b1[tid];
        for (int cc = 0; cc < 64; ++cc) a += sh[cc] * w1[tid * 64 + cc];
        e1[tid] = a > 0.f ? a : 0.f;
    }
    __syncthreads();
    if (tid == 0) {
        float a = b2[c];
        #pragma unroll
        for (int j = 0; j < 8; ++j) a += e1[j] * w2[c * 8 + j];
        ev[0] = 1.f / (1.f + expf(-a));
    }
    __syncthreads();

    int t = blockIdx.x * 256 + tid;      // over SZ/8
    float f = 4.f * (1.f + ev[0]);
    u16x8 av = *(const u16x8*)(x2 + (size_t)t * 8);
    u16x8 bv = *(const u16x8*)(y3 + (size_t)t * 8);
    float4 o0, o1;
    o0.x = f * bf2f(av[0]) * bf2f(bv[0]); o0.y = f * bf2f(av[1]) * bf2f(bv[1]);
    o0.z = f * bf2f(av[2]) * bf2f(bv[2]); o0.w = f * bf2f(av[3]) * bf2f(bv[3]);
    o1.x = f * bf2f(av[4]) * bf2f(bv[4]); o1.y = f * bf2f(av[5]) * bf2f(bv[5]);
    o1.z = f * bf2f(av[6]) * bf2f(bv[6]); o1.w = f * bf2f(av[7]) * bf2f(bv[7]);
    *(float4*)(out + (size_t)t * 8)     = o0;
    *(float4*)(out + (size_t)t * 8 + 4) = o1;
}

// ---------------------------------------------------------------------------
extern "C" void kernel_launch(void* const* d_in, const int* in_sizes, int n_in,
                              void* d_out, int out_size, void* d_ws, size_t ws_size,
                              hipStream_t stream) {
    const float* x     = (const float*)d_in[0];
    const float* fc1w  = (const float*)d_in[1];
    const float* fc1b  = (const float*)d_in[2];
    const float* fc2w  = (const float*)d_in[3];
    const float* fc2b  = (const float*)d_in[4];
    const float* fc3w  = (const float*)d_in[5];
    const float* fc3b  = (const float*)d_in[6];
    const float* fc4w  = (const float*)d_in[7];
    const float* fc4b  = (const float*)d_in[8];
    const float* fc5w  = (const float*)d_in[9];
    const float* fc5b  = (const float*)d_in[10];
    const float* lng   = (const float*)d_in[11];
    const float* lnb   = (const float*)d_in[12];
    const float* pcw   = (const float*)d_in[13];
    const float* dww   = (const float*)d_in[14];
    const float* dwb   = (const float*)d_in[15];
    const float* dwbng = (const float*)d_in[16];
    const float* dwbnb = (const float*)d_in[17];
    const float* ddw   = (const float*)d_in[18];
    const float* ddbng = (const float*)d_in[19];
    const float* ddbnb = (const float*)d_in[20];
    const float* sew1  = (const float*)d_in[21];
    const float* seb1  = (const float*)d_in[22];
    const float* sew2  = (const float*)d_in[23];
    const float* seb2  = (const float*)d_in[24];

    float* out = (float*)d_out;
    u16* wsu = (u16*)d_ws;
    u16* bufA = wsu;                     // xn -> x2
    u16* bufB = wsu + (size_t)SZ;        // t1 -> d1
    u16* bufC = wsu + (size_t)2 * SZ;    // t2 -> d2
    u16* bufD = wsu + (size_t)3 * SZ;    // x1 -> y3
    float* st = (float*)(wsu + (size_t)4 * SZ);
    float* psumA = st;           // 2048
    float* psqA  = st + 2048;    // 2048
    float* psumB = st + 4096;    // 2048
    float* psqB  = st + 6144;    // 2048
    float* svec  = st + 8192;    // 2048
    float* pqv   = st + 10240;   // 128

    dim3 blk(256);
    dim3 blk512(512);
    const float* nil = nullptr;

    // xn = transpose(x) -> bf16
    k_transpose<<<NB * (NHW / 64), blk, 0, stream>>>(x, bufA);
    // P,Q for folded LN
    k_pq<<<1, 64, 0, stream>>>(fc5w, lng, lnb, pqv);
    // t1,t2 = gelu(fc1(roll_h xn)), gelu(fc3(roll_w- xn))  [512 thr, 128 pos]
    k_mfc2<<<NPOS / 128, blk512, 0, stream>>>(bufA, fc1w, fc1b, fc3w, fc3b, bufB, bufC);
    // x1 = fused fc2+fc4+LN+fc5 (+xn residuals)  [512 thr, 128 pos]
    k_ffuse<<<NPOS / 128, blk512, 0, stream>>>(bufB, bufC, bufA, fc2w, fc2b, fc4w, fc4b,
                                               fc5w, lng, pqv, fc5b, bufD);
    // x2 = pc(x1)  [512 thr]
    k_mfc<false><<<NPOS / 128, blk512, 0, stream>>>(bufD, pcw, nil, nil, nil, nil, bufA);
    // d1 = dwconv3x3(x2, dil=1) + dw_b   [stats -> psumA]
    k_dwlds<1, true, false><<<2048, blk, 0, stream>>>(bufA, dww, dwb, nil, nil, nil, nil, bufB, psumA, psqA);
    // d2 = dwconv3x3(relu(bn1(d1)), dil=2)   [bn1 inline; stats -> psumB]
    k_dwlds<2, false, true><<<2048, blk, 0, stream>>>(bufB, ddw, nil, psumA, psqA, dwbng, dwbnb, bufC, psumB, psqB);
    // y3 = pc(relu(bn2(d2)))   [bn2 inline]
    k_mfc<true><<<NPOS / 128, blk512, 0, stream>>>(bufC, pcw, psumB, psqB, ddbng, ddbnb, bufD);
    // SE + final: out = 4*x2*y3*(1+e)
    k_se_reduce<<<NB * NC * 4, blk, 0, stream>>>(bufA, bufD, svec);
    k_final8<<<SZ / 2048, blk, 0, stream>>>(bufA, bufD, svec, sew1, seb1, sew2, seb2, out);
}

// Round 15
// 140.667 us; speedup vs baseline: 1.3125x; 1.0041x over previous
//
#include <hip/hip_runtime.h>

// Problem constants (fixed by the reference)
constexpr int NB  = 8;
constexpr int NC  = 64;
constexpr int NH  = 128;
constexpr int NW  = 128;
constexpr int NHW = NH * NW;          // 16384
constexpr int CHW = NC * NHW;         // 1048576
constexpr int SZ  = NB * CHW;         // 8388608 elements per tensor
constexpr int NPOS = NB * NHW;        // 131072 spatial positions
constexpr float EPS = 1e-5f;

typedef unsigned short u16;
using bf8   = __attribute__((ext_vector_type(8))) short;   // 8 bf16 = 4 VGPR
using u16x8 = __attribute__((ext_vector_type(8))) u16;
using u16x4 = __attribute__((ext_vector_type(4))) u16;
using f32x4 = __attribute__((ext_vector_type(4))) float;

static __device__ inline short f2bf(float f) {
    union { float f; unsigned int u; } v; v.f = f;
    unsigned int r = v.u + 0x7fffu + ((v.u >> 16) & 1u);   // RNE
    return (short)(r >> 16);
}
static __device__ inline float bf2f(u16 u) {
    union { unsigned int i; float f; } v; v.i = ((unsigned int)u) << 16;
    return v.f;
}

// ---------------------------------------------------------------------------
// (B,N,C) fp32 -> (B,C,H,W) bf16 transpose, LDS-tiled
__global__ void k_transpose(const float* __restrict__ x, u16* __restrict__ xn) {
    __shared__ float t[64 * 65];
    int b   = blockIdx.x >> 8;
    int hw0 = (blockIdx.x & 255) << 6;
    int tid = threadIdx.x;
    #pragma unroll
    for (int k = 0; k < 16; ++k) {
        int idx = tid + (k << 8);
        int c = idx & 63, hwl = idx >> 6;
        t[c * 65 + hwl] = x[((size_t)b * NHW + hw0 + hwl) * NC + c];
    }
    __syncthreads();
    #pragma unroll
    for (int k = 0; k < 16; ++k) {
        int idx = tid + (k << 8);
        int hwl = idx & 63, c = idx >> 6;
        xn[(size_t)(b * NC + c) * NHW + hw0 + hwl] = (u16)f2bf(t[c * 65 + hwl]);
    }
}

// ---------------------------------------------------------------------------
// Tiny: P[d] = sum_c g[c]*w5[c][d], Q[d] = sum_c b[c]*w5[c][d]
__global__ void k_pq(const float* __restrict__ w5, const float* __restrict__ lng,
                     const float* __restrict__ lnb, float* __restrict__ PQ) {
    int d = threadIdx.x;   // 64
    float P = 0.f, Q = 0.f;
    for (int c = 0; c < 128; ++c) {
        float wv = w5[c * 64 + d];
        P += lng[c] * wv;
        Q += lnb[c] * wv;
    }
    PQ[d] = P; PQ[64 + d] = Q;
}

// ---------------------------------------------------------------------------
// DUAL channel-linear, swapped operands (D[pos][d], u16x4 stores).
// 512 threads = 128 pos/block; XCD-chunk swizzle (1024 blocks, 128/b -> one b
// per XCD: xn_b = 2 MB fits the 4 MB per-XCD L2, gathers become L2-hits).
__global__ __launch_bounds__(512) void
k_mfc2(const u16* __restrict__ xn,
       const float* __restrict__ w1, const float* __restrict__ b1,
       const float* __restrict__ w3, const float* __restrict__ b3,
       u16* __restrict__ t1, u16* __restrict__ t2) {
    __shared__ short wA[64 * 64];   // fc1w [d][c] swz
    __shared__ short wB[64 * 64];   // fc3w [d][c] swz
    int tid = threadIdx.x;
    int l = tid & 63, wv = tid >> 6;    // wv 0..7
    int q = l >> 4, col = l & 15;
    int bid = ((blockIdx.x & 7) << 7) | (blockIdx.x >> 3);  // XCD chunk swizzle (1024 = 8*128)

    {
        const float* wsrc = (wv < 4) ? w1 : w3;
        short* wdst = (wv < 4) ? wA : wB;
        int wv4 = wv & 3;
        #pragma unroll
        for (int i = 0; i < 8; ++i) {
            int c0 = wv4 * 2 + i * 8;
            unsigned int pk = (unsigned int)(u16)f2bf(wsrc[c0 * 64 + l]) |
                              ((unsigned int)(u16)f2bf(wsrc[(c0 + 1) * 64 + l]) << 16);
            *(unsigned int*)&wdst[l * 64 + (c0 ^ ((l & 7) << 3))] = pk;
        }
    }
    __syncthreads();

    int p  = bid * 128 + wv * 16 + col;
    int b  = p >> 14;
    int hw = p & (NHW - 1);
    int h  = hw >> 7, w = hw & 127;
    const u16* inb = xn + (size_t)b * CHW;

    f32x4 acc1[4], acc2[4];
    #pragma unroll
    for (int dt = 0; dt < 4; ++dt) {
        acc1[dt] = (f32x4){0.f, 0.f, 0.f, 0.f};
        acc2[dt] = (f32x4){0.f, 0.f, 0.f, 0.f};
    }
    #pragma unroll
    for (int ks = 0; ks < 2; ++ks) {
        bf8 f1, f2;
        #pragma unroll
        for (int j = 0; j < 8; ++j) {
            int c = ks * 32 + q * 8 + j;
            f1[j] = (short)inb[c * NHW + (((h - c) & 127) << 7) + w];   // roll_h +1
            f2[j] = (short)inb[c * NHW + (h << 7) + ((w + c) & 127)];   // roll_w -1
        }
        #pragma unroll
        for (int dt = 0; dt < 4; ++dt) {
            int d = dt * 16 + col;
            int wo = (ks * 32 + q * 8) ^ ((d & 7) << 3);
            acc1[dt] = __builtin_amdgcn_mfma_f32_16x16x32_bf16(f1, *(bf8*)&wA[d * 64 + wo], acc1[dt], 0, 0, 0);
            acc2[dt] = __builtin_amdgcn_mfma_f32_16x16x32_bf16(f2, *(bf8*)&wB[d * 64 + wo], acc2[dt], 0, 0, 0);
        }
    }

    // D[row=pos][col=d]: lane (q,col) holds pos = q*4+r for d = dt*16+col
    int hwst = (bid * 128 + wv * 16 + q * 4) & (NHW - 1);
    size_t ob = (size_t)b * CHW + hwst;
    #pragma unroll
    for (int dt = 0; dt < 4; ++dt) {
        int d = dt * 16 + col;
        float bb1 = b1[d], bb3 = b3[d];
        u16x4 o1v, o2v;
        #pragma unroll
        for (int r = 0; r < 4; ++r) {
            float v1 = acc1[dt][r] + bb1;
            v1 = 0.5f * v1 * (1.f + erff(v1 * 0.70710678118654752f));
            float v2 = acc2[dt][r] + bb3;
            v2 = 0.5f * v2 * (1.f + erff(v2 * 0.70710678118654752f));
            o1v[r] = (u16)f2bf(v1);
            o2v[r] = (u16)f2bf(v2);
        }
        *(u16x4*)&t1[ob + (size_t)d * NHW] = o1v;
        *(u16x4*)&t2[ob + (size_t)d * NHW] = o2v;
    }
}

// ---------------------------------------------------------------------------
// FUSED fc2 + fc4 + LayerNorm + fc5 (+xn residuals). 512 threads = 128 pos.
// XCD-chunk swizzle: one b per XCD (t1+t2+xn per b = 6 MB vs 4 MB L2).
__global__ __launch_bounds__(512) void
k_ffuse(const u16* __restrict__ t1, const u16* __restrict__ t2,
        const u16* __restrict__ xnb,
        const float* __restrict__ fc2w, const float* __restrict__ fc2b,
        const float* __restrict__ fc4w, const float* __restrict__ fc4b,
        const float* __restrict__ w5, const float* __restrict__ lng,
        const float* __restrict__ PQ, const float* __restrict__ b5,
        u16* __restrict__ x1out) {
    __shared__ short wA[64 * 64];     // fc2w [d][c] swz
    __shared__ short wB[64 * 64];     // fc4w [d][c] swz
    __shared__ short wG[64 * 128];    // (g.*w5)[d][c'] swz
    __shared__ short xt[128 * 140];   // per-position concat(x_1,x_2) bf16

    int tid = threadIdx.x;
    int l = tid & 63, wv = tid >> 6;   // wv 0..7
    int q = l >> 4, col = l & 15;
    int bid = ((blockIdx.x & 7) << 7) | (blockIdx.x >> 3);  // XCD chunk swizzle

    {
        const float* wsrc = (wv < 4) ? fc2w : fc4w;
        short* wdst = (wv < 4) ? wA : wB;
        int wv4 = wv & 3;
        #pragma unroll
        for (int i = 0; i < 8; ++i) {
            int c0 = wv4 * 2 + i * 8;
            unsigned int pk = (unsigned int)(u16)f2bf(wsrc[c0 * 64 + l]) |
                              ((unsigned int)(u16)f2bf(wsrc[(c0 + 1) * 64 + l]) << 16);
            *(unsigned int*)&wdst[l * 64 + (c0 ^ ((l & 7) << 3))] = pk;
        }
    }
    #pragma unroll
    for (int i = 0; i < 8; ++i) {
        int c0 = wv * 2 + i * 16;      // 8 waves x 8 iters cover even 0..126
        unsigned int pk = (unsigned int)(u16)f2bf(lng[c0] * w5[c0 * 64 + l]) |
                          ((unsigned int)(u16)f2bf(lng[c0 + 1] * w5[(c0 + 1) * 64 + l]) << 16);
        *(unsigned int*)&wG[l * 128 + (c0 ^ ((l & 7) << 3))] = pk;
    }
    __syncthreads();

    int p  = bid * 128 + wv * 16 + col;
    int b  = p >> 14;
    int hw = p & (NHW - 1);
    int h  = hw >> 7, w = hw & 127;
    size_t base = (size_t)b * CHW;
    int pos = wv * 16 + col;           // 0..127

    // fc2 on roll_w(t1,+1), fc4 on roll_h(t2,+1)
    f32x4 acc1[4], acc2[4];
    #pragma unroll
    for (int dt = 0; dt < 4; ++dt) {
        acc1[dt] = (f32x4){0.f, 0.f, 0.f, 0.f};
        acc2[dt] = (f32x4){0.f, 0.f, 0.f, 0.f};
    }
    #pragma unroll
    for (int ks = 0; ks < 2; ++ks) {
        bf8 f1, f2;
        #pragma unroll
        for (int j = 0; j < 8; ++j) {
            int c = ks * 32 + q * 8 + j;
            f1[j] = (short)t1[base + c * NHW + (h << 7) + ((w - c) & 127)];
            f2[j] = (short)t2[base + c * NHW + (((h - c) & 127) << 7) + w];
        }
        #pragma unroll
        for (int dt = 0; dt < 4; ++dt) {
            int d = dt * 16 + col;
            int wo = (ks * 32 + q * 8) ^ ((d & 7) << 3);
            acc1[dt] = __builtin_amdgcn_mfma_f32_16x16x32_bf16(*(bf8*)&wA[d * 64 + wo], f1, acc1[dt], 0, 0, 0);
            acc2[dt] = __builtin_amdgcn_mfma_f32_16x16x32_bf16(*(bf8*)&wB[d * 64 + wo], f2, acc2[dt], 0, 0, 0);
        }
    }

    // xn residuals for this lane's 16 (d, pos) outputs
    float xr[16];
    #pragma unroll
    for (int dt = 0; dt < 4; ++dt)
        #pragma unroll
        for (int r = 0; r < 4; ++r)
            xr[dt * 4 + r] = bf2f(xnb[base + (size_t)(dt * 16 + q * 4 + r) * NHW + hw]);

    // x_1/x_2 values, LN partial stats, write to xt (bf16)
    float s = 0.f, sq = 0.f;
    #pragma unroll
    for (int dt = 0; dt < 4; ++dt) {
        float v1[4], v2[4];
        #pragma unroll
        for (int r = 0; r < 4; ++r) {
            int d = dt * 16 + q * 4 + r;
            v1[r] = acc1[dt][r] + fc2b[d] + xr[dt * 4 + r];
            v2[r] = acc2[dt][r] + fc4b[d] + xr[dt * 4 + r];
            s += v1[r] + v2[r];
            sq += v1[r] * v1[r] + v2[r] * v2[r];
        }
        unsigned int pk0 = (unsigned int)(u16)f2bf(v1[0]) | ((unsigned int)(u16)f2bf(v1[1]) << 16);
        unsigned int pk1 = (unsigned int)(u16)f2bf(v1[2]) | ((unsigned int)(u16)f2bf(v1[3]) << 16);
        *(uint2*)&xt[pos * 140 + dt * 16 + q * 4] = make_uint2(pk0, pk1);
        unsigned int pk2 = (unsigned int)(u16)f2bf(v2[0]) | ((unsigned int)(u16)f2bf(v2[1]) << 16);
        unsigned int pk3 = (unsigned int)(u16)f2bf(v2[2]) | ((unsigned int)(u16)f2bf(v2[3]) << 16);
        *(uint2*)&xt[pos * 140 + 64 + dt * 16 + q * 4] = make_uint2(pk2, pk3);
    }
    s  += __shfl_xor(s, 16);  s += __shfl_xor(s, 32);
    sq += __shfl_xor(sq, 16); sq += __shfl_xor(sq, 32);
    float m    = s * (1.f / 128.f);
    float var  = sq * (1.f / 128.f) - m * m;
    float rstd = rsqrtf(var + EPS);
    float mr   = m * rstd;
    __syncthreads();

    // fc5 (K=128) from xt
    f32x4 acc[4];
    #pragma unroll
    for (int dt = 0; dt < 4; ++dt) acc[dt] = (f32x4){0.f, 0.f, 0.f, 0.f};
    #pragma unroll
    for (int ks = 0; ks < 4; ++ks) {
        bf8 bfr = *(bf8*)&xt[pos * 140 + ks * 32 + q * 8];
        #pragma unroll
        for (int dt = 0; dt < 4; ++dt) {
            int d = dt * 16 + col;
            bf8 afr = *(bf8*)&wG[d * 128 + ((ks * 32 + q * 8) ^ ((d & 7) << 3))];
            acc[dt] = __builtin_amdgcn_mfma_f32_16x16x32_bf16(afr, bfr, acc[dt], 0, 0, 0);
        }
    }

    size_t obase = base + hw;
    #pragma unroll
    for (int dt = 0; dt < 4; ++dt) {
        #pragma unroll
        for (int r = 0; r < 4; ++r) {
            int d = dt * 16 + q * 4 + r;
            float val = rstd * acc[dt][r] + PQ[64 + d] - mr * PQ[d] + b5[d] + xr[dt * 4 + r];
            x1out[obase + (size_t)d * NHW] = (u16)f2bf(val);
        }
    }
}

// ---------------------------------------------------------------------------
// MFMA pointwise conv (K=64), swapped operands -> u16x4 stores. 512 threads.
// SEPART: also accumulate per-block partials of x2*y3 per channel d (the SE
// reduction folded into the epilogue; y3 already in registers).
template<bool BNRELU_IN, bool SEPART>
__global__ __launch_bounds__(512) void
k_mfc(const u16* __restrict__ in, const float* __restrict__ wgt,
      const float* __restrict__ psum, const float* __restrict__ psq,
      const float* __restrict__ bng, const float* __restrict__ bnb,
      const u16* __restrict__ x2in, float* __restrict__ gpart,
      u16* __restrict__ out) {
    __shared__ short wt[64 * 64];
    __shared__ float scl[64], sft[64];
    __shared__ float spart[8][64];
    int tid = threadIdx.x;
    int l = tid & 63, wv = tid >> 6;   // wv 0..7
    int q = l >> 4, col = l & 15;
    int bid = ((blockIdx.x & 7) << 7) | (blockIdx.x >> 3);  // XCD chunk swizzle

    #pragma unroll
    for (int i = 0; i < 8; ++i) {
        int d = wv * 8 + i;
        wt[d * 64 + (l ^ ((d & 7) << 3))] = f2bf(wgt[d * 64 + l]);  // wgt is [d][c]
    }
    if (BNRELU_IN && tid < 64) {
        float s = 0.f, qv = 0.f;
        #pragma unroll
        for (int i = 0; i < 32; ++i) {
            int bb = i >> 2, j = i & 3;
            int idx = ((bb * 64 + tid) << 2) + j;
            s += psum[idx]; qv += psq[idx];
        }
        const float inv = 1.f / (float)(NB * NHW);
        float m = s * inv;
        float var = qv * inv - m * m;
        float rs = rsqrtf(var + EPS);
        float sc = rs * bng[tid];
        scl[tid] = sc;
        sft[tid] = bnb[tid] - m * sc;
    }
    __syncthreads();

    int p  = bid * 128 + wv * 16 + col;
    int b  = p >> 14;
    int hw = p & (NHW - 1);
    const u16* inb = in + (size_t)b * CHW;

    f32x4 acc[4];
    #pragma unroll
    for (int dt = 0; dt < 4; ++dt) acc[dt] = (f32x4){0.f, 0.f, 0.f, 0.f};

    #pragma unroll
    for (int ks = 0; ks < 2; ++ks) {
        bf8 bfr;
        #pragma unroll
        for (int j = 0; j < 8; ++j) {
            int c = ks * 32 + q * 8 + j;
            u16 raw = inb[c * NHW + hw];
            if (BNRELU_IN) {
                float v = fmaxf(bf2f(raw) * scl[c] + sft[c], 0.f);
                bfr[j] = f2bf(v);
            } else {
                bfr[j] = (short)raw;
            }
        }
        #pragma unroll
        for (int dt = 0; dt < 4; ++dt) {
            int d = dt * 16 + col;
            bf8 afr = *(bf8*)&wt[d * 64 + ((ks * 32 + q * 8) ^ ((d & 7) << 3))];
            acc[dt] = __builtin_amdgcn_mfma_f32_16x16x32_bf16(bfr, afr, acc[dt], 0, 0, 0);
        }
    }

    // D[row=pos][col=d]: pos = q*4+r, d = dt*16+col
    int hwst = (bid * 128 + wv * 16 + q * 4) & (NHW - 1);
    size_t ob = (size_t)b * CHW + hwst;
    float pp[4] = {0.f, 0.f, 0.f, 0.f};
    #pragma unroll
    for (int dt = 0; dt < 4; ++dt) {
        int d = dt * 16 + col;
        u16x4 ov;
        #pragma unroll
        for (int r = 0; r < 4; ++r) ov[r] = (u16)f2bf(acc[dt][r]);
        *(u16x4*)&out[ob + (size_t)d * NHW] = ov;
        if (SEPART) {
            u16x4 xv = *(const u16x4*)&x2in[ob + (size_t)d * NHW];
            #pragma unroll
            for (int r = 0; r < 4; ++r) pp[dt] += bf2f(xv[r]) * bf2f(ov[r]);
        }
    }

    if (SEPART) {
        #pragma unroll
        for (int dt = 0; dt < 4; ++dt) {
            pp[dt] += __shfl_xor(pp[dt], 16);
            pp[dt] += __shfl_xor(pp[dt], 32);
        }
        if (l < 16) {
            #pragma unroll
            for (int dt = 0; dt < 4; ++dt) spart[wv][dt * 16 + l] = pp[dt];
        }
        __syncthreads();
        if (tid < 64) {
            float s = 0.f;
            #pragma unroll
            for (int w8 = 0; w8 < 8; ++w8) s += spart[w8][tid];
            gpart[(size_t)bid * 64 + tid] = s;   // indexed by WORK id (pos chunk)
        }
    }
}

// ---------------------------------------------------------------------------
// svec[b*64+c] = (4/NHW) * sum over the b's 128 block-partials
__global__ void k_se_fin(const float* __restrict__ gpart, float* __restrict__ svec) {
    int b = blockIdx.x, c = threadIdx.x;   // 8 blocks x 64 threads
    float s = 0.f;
    for (int k = 0; k < 128; ++k) s += gpart[(size_t)(b * 128 + k) * 64 + c];
    svec[b * 64 + c] = s * (4.f / (float)NHW);
}

// ---------------------------------------------------------------------------
// Depthwise 3x3 conv, LDS-tiled, bf16 in/out. Block = 32 rows of one plane.
template<int DIL, bool HASBIAS, bool BNIN>
__global__ __launch_bounds__(256) void
k_dwlds(const u16* __restrict__ in, const float* __restrict__ wgt,
        const float* __restrict__ bias,
        const float* __restrict__ psumIn, const float* __restrict__ psqIn,
        const float* __restrict__ bng, const float* __restrict__ bnb,
        u16* __restrict__ out, float* __restrict__ psumOut, float* __restrict__ psqOut) {
    constexpr int STR = 136;                  // 4 pad | 128 | 4 pad
    __shared__ float tile[36 * STR];
    __shared__ float ss[256], sq[256];

    int blk = ((blockIdx.x & 7) << 8) | (blockIdx.x >> 3);  // XCD chunk swizzle
    int q   = blk & 3;
    int bc  = blk >> 2;
    int c   = bc & 63;
    int r0  = q * 32;
    int tid = threadIdx.x;
    const u16* ip = in + (size_t)bc * NHW;

    float scale = 0.f, shift = 0.f;
    if (BNIN) {
        float s = 0.f, qv = 0.f;
        #pragma unroll
        for (int i = 0; i < 32; ++i) {
            int bb = i >> 2, j = i & 3;
            int idx = ((bb * 64 + c) << 2) + j;
            s += psumIn[idx]; qv += psqIn[idx];
        }
        const float inv = 1.f / (float)(NB * NHW);
        float m = s * inv;
        float var = qv * inv - m * m;
        float rs = rsqrtf(var + EPS);
        scale = rs * bng[c];
        shift = bnb[c] - m * scale;
    }

    #pragma unroll 1
    for (int idx = tid; idx < 36 * 16; idx += 256) {
        int lr = idx >> 4, u = idx & 15;
        int gr = r0 - 2 + lr;
        float v[8] = {0.f, 0.f, 0.f, 0.f, 0.f, 0.f, 0.f, 0.f};
        if (gr >= 0 && gr < NH) {
            u16x8 raw = *(const u16x8*)(ip + gr * NW + u * 8);
            #pragma unroll
            for (int j = 0; j < 8; ++j) {
                float f = bf2f(raw[j]);
                if (BNIN) f = fmaxf(f * scale + shift, 0.f);
                v[j] = f;
            }
        }
        *(float4*)&tile[lr * STR + 4 + u * 8]     = make_float4(v[0], v[1], v[2], v[3]);
        *(float4*)&tile[lr * STR + 4 + u * 8 + 4] = make_float4(v[4], v[5], v[6], v[7]);
        if (u == 0)  *(float4*)&tile[lr * STR]       = make_float4(0.f, 0.f, 0.f, 0.f);
        if (u == 15) *(float4*)&tile[lr * STR + 132] = make_float4(0.f, 0.f, 0.f, 0.f);
    }
    __syncthreads();

    float wc[9];
    #pragma unroll
    for (int k = 0; k < 9; ++k) wc[k] = wgt[c * 9 + k];

    int row  = tid >> 3;
    int col0 = (tid & 7) * 16;
    float o[16];
    float bb = HASBIAS ? bias[c] : 0.f;
    #pragma unroll
    for (int j = 0; j < 16; ++j) o[j] = bb;

    #pragma unroll
    for (int i = 0; i < 3; ++i) {
        const float* rp = &tile[(row + 2 + (i - 1) * DIL) * STR + 4 + col0];
        float4 A  = *(const float4*)(rp - 4);
        float4 B0 = *(const float4*)(rp);
        float4 B1 = *(const float4*)(rp + 4);
        float4 B2 = *(const float4*)(rp + 8);
        float4 B3 = *(const float4*)(rp + 12);
        float4 Cc = *(const float4*)(rp + 16);
        float ww[24] = {A.x,A.y,A.z,A.w, B0.x,B0.y,B0.z,B0.w, B1.x,B1.y,B1.z,B1.w,
                        B2.x,B2.y,B2.z,B2.w, B3.x,B3.y,B3.z,B3.w, Cc.x,Cc.y,Cc.z,Cc.w};
        float w0 = wc[3 * i], w1 = wc[3 * i + 1], w2 = wc[3 * i + 2];
        #pragma unroll
        for (int j = 0; j < 16; ++j)
            o[j] += w0 * ww[4 + j - DIL] + w1 * ww[4 + j] + w2 * ww[4 + j + DIL];
    }

    u16* op = out + (size_t)bc * NHW + (r0 + row) * NW + col0;
    u16x8 o1, o2;
    #pragma unroll
    for (int j = 0; j < 8; ++j) { o1[j] = (u16)f2bf(o[j]); o2[j] = (u16)f2bf(o[8 + j]); }
    *(u16x8*)(op)     = o1;
    *(u16x8*)(op + 8) = o2;

    float s = 0.f, qq = 0.f;
    #pragma unroll
    for (int j = 0; j < 16; ++j) { s += o[j]; qq += o[j] * o[j]; }
    ss[tid] = s; sq[tid] = qq; __syncthreads();
    for (int off = 128; off > 0; off >>= 1) {
        if (tid < off) { ss[tid] += ss[tid + off]; sq[tid] += sq[tid + off]; }
        __syncthreads();
    }
    if (tid == 0) { psumOut[blk] = ss[0]; psqOut[blk] = sq[0]; }
}

// ---------------------------------------------------------------------------
// out = 4*x2*y3*(1+e); SE-MLP folded in (block-uniform (b,c)); svec prescaled.
__global__ void k_final8(const u16* __restrict__ x2, const u16* __restrict__ y3,
                         const float* __restrict__ svec,
                         const float* __restrict__ w1, const float* __restrict__ b1,
                         const float* __restrict__ w2, const float* __restrict__ b2,
                         float* __restrict__ out) {
    __shared__ float sh[64], e1[8], ev[1];
    int tid = threadIdx.x;
    int bc = blockIdx.x >> 3;            // block covers 2048 elems = 1/8 plane
    int b  = bc >> 6, c = bc & 63;

    if (tid < 64) sh[tid] = svec[b * 64 + tid];
    __syncthreads();
    if (tid < 8) {
        float a = b1[tid];
        for (int cc = 0; cc < 64; ++cc) a += sh[cc] * w1[tid * 64 + cc];
        e1[tid] = a > 0.f ? a : 0.f;
    }
    __syncthreads();
    if (tid == 0) {
        float a = b2[c];
        #pragma unroll
        for (int j = 0; j < 8; ++j) a += e1[j] * w2[c * 8 + j];
        ev[0] = 1.f / (1.f + expf(-a));
    }
    __syncthreads();

    int t = blockIdx.x * 256 + tid;      // over SZ/8
    float f = 4.f * (1.f + ev[0]);
    u16x8 av = *(const u16x8*)(x2 + (size_t)t * 8);
    u16x8 bv = *(const u16x8*)(y3 + (size_t)t * 8);
    float4 o0, o1;
    o0.x = f * bf2f(av[0]) * bf2f(bv[0]); o0.y = f * bf2f(av[1]) * bf2f(bv[1]);
    o0.z = f * bf2f(av[2]) * bf2f(bv[2]); o0.w = f * bf2f(av[3]) * bf2f(bv[3]);
    o1.x = f * bf2f(av[4]) * bf2f(bv[4]); o1.y = f * bf2f(av[5]) * bf2f(bv[5]);
    o1.z = f * bf2f(av[6]) * bf2f(bv[6]); o1.w = f * bf2f(av[7]) * bf2f(bv[7]);
    *(float4*)(out + (size_t)t * 8)     = o0;
    *(float4*)(out + (size_t)t * 8 + 4) = o1;
}

// ---------------------------------------------------------------------------
extern "C" void kernel_launch(void* const* d_in, const int* in_sizes, int n_in,
                              void* d_out, int out_size, void* d_ws, size_t ws_size,
                              hipStream_t stream) {
    const float* x     = (const float*)d_in[0];
    const float* fc1w  = (const float*)d_in[1];
    const float* fc1b  = (const float*)d_in[2];
    const float* fc2w  = (const float*)d_in[3];
    const float* fc2b  = (const float*)d_in[4];
    const float* fc3w  = (const float*)d_in[5];
    const float* fc3b  = (const float*)d_in[6];
    const float* fc4w  = (const float*)d_in[7];
    const float* fc4b  = (const float*)d_in[8];
    const float* fc5w  = (const float*)d_in[9];
    const float* fc5b  = (const float*)d_in[10];
    const float* lng   = (const float*)d_in[11];
    const float* lnb   = (const float*)d_in[12];
    const float* pcw   = (const float*)d_in[13];
    const float* dww   = (const float*)d_in[14];
    const float* dwb   = (const float*)d_in[15];
    const float* dwbng = (const float*)d_in[16];
    const float* dwbnb = (const float*)d_in[17];
    const float* ddw   = (const float*)d_in[18];
    const float* ddbng = (const float*)d_in[19];
    const float* ddbnb = (const float*)d_in[20];
    const float* sew1  = (const float*)d_in[21];
    const float* seb1  = (const float*)d_in[22];
    const float* sew2  = (const float*)d_in[23];
    const float* seb2  = (const float*)d_in[24];

    float* out = (float*)d_out;
    u16* wsu = (u16*)d_ws;
    u16* bufA = wsu;                     // xn -> x2
    u16* bufB = wsu + (size_t)SZ;        // t1 -> d1
    u16* bufC = wsu + (size_t)2 * SZ;    // t2 -> d2
    u16* bufD = wsu + (size_t)3 * SZ;    // x1 -> y3
    float* st = (float*)(wsu + (size_t)4 * SZ);
    float* psumA = st;           // 2048
    float* psqA  = st + 2048;    // 2048
    float* psumB = st + 4096;    // 2048
    float* psqB  = st + 6144;    // 2048
    float* svec  = st + 8192;    // 512
    float* pqv   = st + 8704;    // 128
    float* gpart = st + 8832;    // 65536 (1024 blocks x 64 ch)

    dim3 blk(256);
    dim3 blk512(512);
    const float* nil = nullptr;
    const u16*   nilu = nullptr;
    float*       nilf = nullptr;

    // xn = transpose(x) -> bf16
    k_transpose<<<NB * (NHW / 64), blk, 0, stream>>>(x, bufA);
    // P,Q for folded LN
    k_pq<<<1, 64, 0, stream>>>(fc5w, lng, lnb, pqv);
    // t1,t2 = gelu(fc1(roll_h xn)), gelu(fc3(roll_w- xn))  [512 thr, XCD swz]
    k_mfc2<<<NPOS / 128, blk512, 0, stream>>>(bufA, fc1w, fc1b, fc3w, fc3b, bufB, bufC);
    // x1 = fused fc2+fc4+LN+fc5 (+xn residuals)  [512 thr, XCD swz]
    k_ffuse<<<NPOS / 128, blk512, 0, stream>>>(bufB, bufC, bufA, fc2w, fc2b, fc4w, fc4b,
                                               fc5w, lng, pqv, fc5b, bufD);
    // x2 = pc(x1)
    k_mfc<false, false><<<NPOS / 128, blk512, 0, stream>>>(bufD, pcw, nil, nil, nil, nil, nilu, nilf, bufA);
    // d1 = dwconv3x3(x2, dil=1) + dw_b   [stats -> psumA]
    k_dwlds<1, true, false><<<2048, blk, 0, stream>>>(bufA, dww, dwb, nil, nil, nil, nil, bufB, psumA, psqA);
    // d2 = dwconv3x3(relu(bn1(d1)), dil=2)   [bn1 inline; stats -> psumB]
    k_dwlds<2, false, true><<<2048, blk, 0, stream>>>(bufB, ddw, nil, psumA, psqA, dwbng, dwbnb, bufC, psumB, psqB);
    // y3 = pc(relu(bn2(d2)))   [bn2 inline; SE partials fused into epilogue]
    k_mfc<true, true><<<NPOS / 128, blk512, 0, stream>>>(bufC, pcw, psumB, psqB, ddbng, ddbnb, bufA, gpart, bufD);
    // SE finalize + final: out = 4*x2*y3*(1+e)
    k_se_fin<<<NB, 64, 0, stream>>>(gpart, svec);
    k_final8<<<SZ / 2048, blk, 0, stream>>>(bufA, bufD, svec, sew1, seb1, sew2, seb2, out);
}

// Round 16
// 138.873 us; speedup vs baseline: 1.3295x; 1.0129x over previous
//
#include <hip/hip_runtime.h>

// Problem constants (fixed by the reference)
constexpr int NB  = 8;
constexpr int NC  = 64;
constexpr int NH  = 128;
constexpr int NW  = 128;
constexpr int NHW = NH * NW;          // 16384
constexpr int CHW = NC * NHW;         // 1048576
constexpr int SZ  = NB * CHW;         // 8388608 elements per tensor
constexpr int NPOS = NB * NHW;        // 131072 spatial positions
constexpr float EPS = 1e-5f;

typedef unsigned short u16;
using bf8   = __attribute__((ext_vector_type(8))) short;   // 8 bf16 = 4 VGPR
using u16x8 = __attribute__((ext_vector_type(8))) u16;
using u16x4 = __attribute__((ext_vector_type(4))) u16;
using f32x4 = __attribute__((ext_vector_type(4))) float;

static __device__ inline short f2bf(float f) {
    union { float f; unsigned int u; } v; v.f = f;
    unsigned int r = v.u + 0x7fffu + ((v.u >> 16) & 1u);   // RNE
    return (short)(r >> 16);
}
static __device__ inline float bf2f(u16 u) {
    union { unsigned int i; float f; } v; v.i = ((unsigned int)u) << 16;
    return v.f;
}

// ---------------------------------------------------------------------------
// (B,N,C) fp32 -> (B,C,H,W) bf16 transpose, LDS-tiled.
// Block 2048 computes the folded-LN P/Q vectors instead (merged k_pq).
__global__ void k_transpose(const float* __restrict__ x, u16* __restrict__ xn,
                            const float* __restrict__ w5, const float* __restrict__ lng,
                            const float* __restrict__ lnb, float* __restrict__ PQ) {
    if (blockIdx.x == 2048) {
        int d = threadIdx.x;
        if (d < 64) {
            float P = 0.f, Q = 0.f;
            for (int c = 0; c < 128; ++c) {
                float wv = w5[c * 64 + d];
                P += lng[c] * wv;
                Q += lnb[c] * wv;
            }
            PQ[d] = P; PQ[64 + d] = Q;
        }
        return;
    }
    __shared__ float t[64 * 65];
    int b   = blockIdx.x >> 8;
    int hw0 = (blockIdx.x & 255) << 6;
    int tid = threadIdx.x;
    #pragma unroll
    for (int k = 0; k < 16; ++k) {
        int idx = tid + (k << 8);
        int c = idx & 63, hwl = idx >> 6;
        t[c * 65 + hwl] = x[((size_t)b * NHW + hw0 + hwl) * NC + c];
    }
    __syncthreads();
    #pragma unroll
    for (int k = 0; k < 16; ++k) {
        int idx = tid + (k << 8);
        int hwl = idx & 63, c = idx >> 6;
        xn[(size_t)(b * NC + c) * NHW + hw0 + hwl] = (u16)f2bf(t[c * 65 + hwl]);
    }
}

// ---------------------------------------------------------------------------
// DUAL channel-linear, swapped operands (D[pos][d], u16x4 stores).
// 512 threads = 128 pos/block; XCD-chunk swizzle.
__global__ __launch_bounds__(512) void
k_mfc2(const u16* __restrict__ xn,
       const float* __restrict__ w1, const float* __restrict__ b1,
       const float* __restrict__ w3, const float* __restrict__ b3,
       u16* __restrict__ t1, u16* __restrict__ t2) {
    __shared__ short wA[64 * 64];   // fc1w [d][c] swz
    __shared__ short wB[64 * 64];   // fc3w [d][c] swz
    int tid = threadIdx.x;
    int l = tid & 63, wv = tid >> 6;    // wv 0..7
    int q = l >> 4, col = l & 15;
    int bid = ((blockIdx.x & 7) << 7) | (blockIdx.x >> 3);  // XCD chunk swizzle

    {
        const float* wsrc = (wv < 4) ? w1 : w3;
        short* wdst = (wv < 4) ? wA : wB;
        int wv4 = wv & 3;
        #pragma unroll
        for (int i = 0; i < 8; ++i) {
            int c0 = wv4 * 2 + i * 8;
            unsigned int pk = (unsigned int)(u16)f2bf(wsrc[c0 * 64 + l]) |
                              ((unsigned int)(u16)f2bf(wsrc[(c0 + 1) * 64 + l]) << 16);
            *(unsigned int*)&wdst[l * 64 + (c0 ^ ((l & 7) << 3))] = pk;
        }
    }
    __syncthreads();

    int p  = bid * 128 + wv * 16 + col;
    int b  = p >> 14;
    int hw = p & (NHW - 1);
    int h  = hw >> 7, w = hw & 127;
    const u16* inb = xn + (size_t)b * CHW;

    f32x4 acc1[4], acc2[4];
    #pragma unroll
    for (int dt = 0; dt < 4; ++dt) {
        acc1[dt] = (f32x4){0.f, 0.f, 0.f, 0.f};
        acc2[dt] = (f32x4){0.f, 0.f, 0.f, 0.f};
    }
    #pragma unroll
    for (int ks = 0; ks < 2; ++ks) {
        bf8 f1, f2;
        #pragma unroll
        for (int j = 0; j < 8; ++j) {
            int c = ks * 32 + q * 8 + j;
            f1[j] = (short)inb[c * NHW + (((h - c) & 127) << 7) + w];   // roll_h +1
            f2[j] = (short)inb[c * NHW + (h << 7) + ((w + c) & 127)];   // roll_w -1
        }
        #pragma unroll
        for (int dt = 0; dt < 4; ++dt) {
            int d = dt * 16 + col;
            int wo = (ks * 32 + q * 8) ^ ((d & 7) << 3);
            acc1[dt] = __builtin_amdgcn_mfma_f32_16x16x32_bf16(f1, *(bf8*)&wA[d * 64 + wo], acc1[dt], 0, 0, 0);
            acc2[dt] = __builtin_amdgcn_mfma_f32_16x16x32_bf16(f2, *(bf8*)&wB[d * 64 + wo], acc2[dt], 0, 0, 0);
        }
    }

    int hwst = (bid * 128 + wv * 16 + q * 4) & (NHW - 1);
    size_t ob = (size_t)b * CHW + hwst;
    #pragma unroll
    for (int dt = 0; dt < 4; ++dt) {
        int d = dt * 16 + col;
        float bb1 = b1[d], bb3 = b3[d];
        u16x4 o1v, o2v;
        #pragma unroll
        for (int r = 0; r < 4; ++r) {
            float v1 = acc1[dt][r] + bb1;
            v1 = 0.5f * v1 * (1.f + erff(v1 * 0.70710678118654752f));
            float v2 = acc2[dt][r] + bb3;
            v2 = 0.5f * v2 * (1.f + erff(v2 * 0.70710678118654752f));
            o1v[r] = (u16)f2bf(v1);
            o2v[r] = (u16)f2bf(v2);
        }
        *(u16x4*)&t1[ob + (size_t)d * NHW] = o1v;
        *(u16x4*)&t2[ob + (size_t)d * NHW] = o2v;
    }
}

// ---------------------------------------------------------------------------
// FUSED fc2 + fc4 + LayerNorm + fc5 (+xn residuals). 512 threads = 128 pos.
// ALL MFMAs swapped (A=input) -> D[pos][d] everywhere: xr residual and final
// stores are u16x4; LN stats per (q,r) row via 16-lane xor reduce.
__global__ __launch_bounds__(512) void
k_ffuse(const u16* __restrict__ t1, const u16* __restrict__ t2,
        const u16* __restrict__ xnb,
        const float* __restrict__ fc2w, const float* __restrict__ fc2b,
        const float* __restrict__ fc4w, const float* __restrict__ fc4b,
        const float* __restrict__ w5, const float* __restrict__ lng,
        const float* __restrict__ PQ, const float* __restrict__ b5,
        u16* __restrict__ x1out) {
    __shared__ short wA[64 * 64];     // fc2w [d][c] swz
    __shared__ short wB[64 * 64];     // fc4w [d][c] swz
    __shared__ short wG[64 * 128];    // (g.*w5)[d][c'] swz
    __shared__ short xt[128 * 140];   // per-position concat(x_1,x_2) bf16

    int tid = threadIdx.x;
    int l = tid & 63, wv = tid >> 6;   // wv 0..7
    int q = l >> 4, col = l & 15;
    int bid = ((blockIdx.x & 7) << 7) | (blockIdx.x >> 3);  // XCD chunk swizzle

    {
        const float* wsrc = (wv < 4) ? fc2w : fc4w;
        short* wdst = (wv < 4) ? wA : wB;
        int wv4 = wv & 3;
        #pragma unroll
        for (int i = 0; i < 8; ++i) {
            int c0 = wv4 * 2 + i * 8;
            unsigned int pk = (unsigned int)(u16)f2bf(wsrc[c0 * 64 + l]) |
                              ((unsigned int)(u16)f2bf(wsrc[(c0 + 1) * 64 + l]) << 16);
            *(unsigned int*)&wdst[l * 64 + (c0 ^ ((l & 7) << 3))] = pk;
        }
    }
    #pragma unroll
    for (int i = 0; i < 8; ++i) {
        int c0 = wv * 2 + i * 16;      // 8 waves x 8 iters cover even 0..126
        unsigned int pk = (unsigned int)(u16)f2bf(lng[c0] * w5[c0 * 64 + l]) |
                          ((unsigned int)(u16)f2bf(lng[c0 + 1] * w5[(c0 + 1) * 64 + l]) << 16);
        *(unsigned int*)&wG[l * 128 + (c0 ^ ((l & 7) << 3))] = pk;
    }
    __syncthreads();

    int p  = bid * 128 + wv * 16 + col;     // gather position (A-frag row = col)
    int b  = p >> 14;
    int hw = p & (NHW - 1);
    int h  = hw >> 7, w = hw & 127;
    size_t base = (size_t)b * CHW;

    // fc2 on roll_w(t1,+1), fc4 on roll_h(t2,+1), SWAPPED -> D[pos][d]
    f32x4 acc1[4], acc2[4];
    #pragma unroll
    for (int dt = 0; dt < 4; ++dt) {
        acc1[dt] = (f32x4){0.f, 0.f, 0.f, 0.f};
        acc2[dt] = (f32x4){0.f, 0.f, 0.f, 0.f};
    }
    #pragma unroll
    for (int ks = 0; ks < 2; ++ks) {
        bf8 f1, f2;
        #pragma unroll
        for (int j = 0; j < 8; ++j) {
            int c = ks * 32 + q * 8 + j;
            f1[j] = (short)t1[base + c * NHW + (h << 7) + ((w - c) & 127)];
            f2[j] = (short)t2[base + c * NHW + (((h - c) & 127) << 7) + w];
        }
        #pragma unroll
        for (int dt = 0; dt < 4; ++dt) {
            int d = dt * 16 + col;
            int wo = (ks * 32 + q * 8) ^ ((d & 7) << 3);
            acc1[dt] = __builtin_amdgcn_mfma_f32_16x16x32_bf16(f1, *(bf8*)&wA[d * 64 + wo], acc1[dt], 0, 0, 0);
            acc2[dt] = __builtin_amdgcn_mfma_f32_16x16x32_bf16(f2, *(bf8*)&wB[d * 64 + wo], acc2[dt], 0, 0, 0);
        }
    }

    // xn residuals, vectorized: lane covers positions q*4+r at d = dt*16+col
    int hwst = (bid * 128 + wv * 16 + q * 4) & (NHW - 1);
    size_t ob = base + hwst;
    u16x4 xr4[4];
    #pragma unroll
    for (int dt = 0; dt < 4; ++dt)
        xr4[dt] = *(const u16x4*)&xnb[ob + (size_t)(dt * 16 + col) * NHW];

    // v1/v2 (pos = q*4+r rows), LN partial stats per r, write xt[pos][d]
    float s[4] = {0.f, 0.f, 0.f, 0.f}, sq[4] = {0.f, 0.f, 0.f, 0.f};
    int posr = wv * 16 + q * 4;            // first of this lane's 4 positions
    #pragma unroll
    for (int dt = 0; dt < 4; ++dt) {
        int d = dt * 16 + col;
        float bb2 = fc2b[d], bb4 = fc4b[d];
        #pragma unroll
        for (int r = 0; r < 4; ++r) {
            float xv = bf2f(xr4[dt][r]);
            float v1 = acc1[dt][r] + bb2 + xv;
            float v2 = acc2[dt][r] + bb4 + xv;
            s[r]  += v1 + v2;
            sq[r] += v1 * v1 + v2 * v2;
            xt[(posr + r) * 140 + d]      = f2bf(v1);
            xt[(posr + r) * 140 + 64 + d] = f2bf(v2);
        }
    }
    // reduce over the 16-lane col group (covers all 128 d per position)
    #pragma unroll
    for (int off = 1; off < 16; off <<= 1) {
        #pragma unroll
        for (int r = 0; r < 4; ++r) {
            s[r]  += __shfl_xor(s[r], off);
            sq[r] += __shfl_xor(sq[r], off);
        }
    }
    float rstd[4], mr[4];
    #pragma unroll
    for (int r = 0; r < 4; ++r) {
        float m   = s[r] * (1.f / 128.f);
        float var = sq[r] * (1.f / 128.f) - m * m;
        rstd[r] = rsqrtf(var + EPS);
        mr[r]   = m * rstd[r];
    }
    __syncthreads();

    // fc5 (K=128) from xt, SWAPPED -> D[pos][d]
    f32x4 acc[4];
    #pragma unroll
    for (int dt = 0; dt < 4; ++dt) acc[dt] = (f32x4){0.f, 0.f, 0.f, 0.f};
    #pragma unroll
    for (int ks = 0; ks < 4; ++ks) {
        bf8 bfr = *(bf8*)&xt[(wv * 16 + col) * 140 + ks * 32 + q * 8];
        #pragma unroll
        for (int dt = 0; dt < 4; ++dt) {
            int d = dt * 16 + col;
            bf8 wfr = *(bf8*)&wG[d * 128 + ((ks * 32 + q * 8) ^ ((d & 7) << 3))];
            acc[dt] = __builtin_amdgcn_mfma_f32_16x16x32_bf16(bfr, wfr, acc[dt], 0, 0, 0);
        }
    }

    // epilogue: rstd/mr already in row layout; stores vectorized
    #pragma unroll
    for (int dt = 0; dt < 4; ++dt) {
        int d = dt * 16 + col;
        float pqd = PQ[d], pqq = PQ[64 + d], b5d = b5[d];
        u16x4 ov;
        #pragma unroll
        for (int r = 0; r < 4; ++r) {
            float val = rstd[r] * acc[dt][r] + pqq - mr[r] * pqd + b5d + bf2f(xr4[dt][r]);
            ov[r] = (u16)f2bf(val);
        }
        *(u16x4*)&x1out[ob + (size_t)d * NHW] = ov;
    }
}

// ---------------------------------------------------------------------------
// MFMA pointwise conv (K=64), swapped operands -> u16x4 stores. 512 threads.
// SEPART: fold SE reduction of x2*y3 into the epilogue.
template<bool BNRELU_IN, bool SEPART>
__global__ __launch_bounds__(512) void
k_mfc(const u16* __restrict__ in, const float* __restrict__ wgt,
      const float* __restrict__ psum, const float* __restrict__ psq,
      const float* __restrict__ bng, const float* __restrict__ bnb,
      const u16* __restrict__ x2in, float* __restrict__ gpart,
      u16* __restrict__ out) {
    __shared__ short wt[64 * 64];
    __shared__ float scl[64], sft[64];
    __shared__ float spart[8][64];
    int tid = threadIdx.x;
    int l = tid & 63, wv = tid >> 6;   // wv 0..7
    int q = l >> 4, col = l & 15;
    int bid = ((blockIdx.x & 7) << 7) | (blockIdx.x >> 3);  // XCD chunk swizzle

    #pragma unroll
    for (int i = 0; i < 8; ++i) {
        int d = wv * 8 + i;
        wt[d * 64 + (l ^ ((d & 7) << 3))] = f2bf(wgt[d * 64 + l]);  // wgt is [d][c]
    }
    if (BNRELU_IN && tid < 64) {
        float s = 0.f, qv = 0.f;
        #pragma unroll
        for (int i = 0; i < 32; ++i) {
            int bb = i >> 2, j = i & 3;
            int idx = ((bb * 64 + tid) << 2) + j;
            s += psum[idx]; qv += psq[idx];
        }
        const float inv = 1.f / (float)(NB * NHW);
        float m = s * inv;
        float var = qv * inv - m * m;
        float rs = rsqrtf(var + EPS);
        float sc = rs * bng[tid];
        scl[tid] = sc;
        sft[tid] = bnb[tid] - m * sc;
    }
    __syncthreads();

    int p  = bid * 128 + wv * 16 + col;
    int b  = p >> 14;
    int hw = p & (NHW - 1);
    const u16* inb = in + (size_t)b * CHW;

    f32x4 acc[4];
    #pragma unroll
    for (int dt = 0; dt < 4; ++dt) acc[dt] = (f32x4){0.f, 0.f, 0.f, 0.f};

    #pragma unroll
    for (int ks = 0; ks < 2; ++ks) {
        bf8 bfr;
        #pragma unroll
        for (int j = 0; j < 8; ++j) {
            int c = ks * 32 + q * 8 + j;
            u16 raw = inb[c * NHW + hw];
            if (BNRELU_IN) {
                float v = fmaxf(bf2f(raw) * scl[c] + sft[c], 0.f);
                bfr[j] = f2bf(v);
            } else {
                bfr[j] = (short)raw;
            }
        }
        #pragma unroll
        for (int dt = 0; dt < 4; ++dt) {
            int d = dt * 16 + col;
            bf8 afr = *(bf8*)&wt[d * 64 + ((ks * 32 + q * 8) ^ ((d & 7) << 3))];
            acc[dt] = __builtin_amdgcn_mfma_f32_16x16x32_bf16(bfr, afr, acc[dt], 0, 0, 0);
        }
    }

    int hwst = (bid * 128 + wv * 16 + q * 4) & (NHW - 1);
    size_t ob = (size_t)b * CHW + hwst;
    float pp[4] = {0.f, 0.f, 0.f, 0.f};
    #pragma unroll
    for (int dt = 0; dt < 4; ++dt) {
        int d = dt * 16 + col;
        u16x4 ov;
        #pragma unroll
        for (int r = 0; r < 4; ++r) ov[r] = (u16)f2bf(acc[dt][r]);
        *(u16x4*)&out[ob + (size_t)d * NHW] = ov;
        if (SEPART) {
            u16x4 xv = *(const u16x4*)&x2in[ob + (size_t)d * NHW];
            #pragma unroll
            for (int r = 0; r < 4; ++r) pp[dt] += bf2f(xv[r]) * bf2f(ov[r]);
        }
    }

    if (SEPART) {
        #pragma unroll
        for (int dt = 0; dt < 4; ++dt) {
            pp[dt] += __shfl_xor(pp[dt], 16);
            pp[dt] += __shfl_xor(pp[dt], 32);
        }
        if (l < 16) {
            #pragma unroll
            for (int dt = 0; dt < 4; ++dt) spart[wv][dt * 16 + l] = pp[dt];
        }
        __syncthreads();
        if (tid < 64) {
            float s = 0.f;
            #pragma unroll
            for (int w8 = 0; w8 < 8; ++w8) s += spart[w8][tid];
            gpart[(size_t)bid * 64 + tid] = s;
        }
    }
}

// ---------------------------------------------------------------------------
// svec[b*64+c] = (4/NHW) * sum over the b's 128 block-partials
__global__ void k_se_fin(const float* __restrict__ gpart, float* __restrict__ svec) {
    int b = blockIdx.x, c = threadIdx.x;   // 8 blocks x 64 threads
    float s = 0.f;
    for (int k = 0; k < 128; ++k) s += gpart[(size_t)(b * 128 + k) * 64 + c];
    svec[b * 64 + c] = s * (4.f / (float)NHW);
}

// ---------------------------------------------------------------------------
// Depthwise 3x3 conv, LDS-tiled, bf16 in/out. Block = 32 rows of one plane.
template<int DIL, bool HASBIAS, bool BNIN>
__global__ __launch_bounds__(256) void
k_dwlds(const u16* __restrict__ in, const float* __restrict__ wgt,
        const float* __restrict__ bias,
        const float* __restrict__ psumIn, const float* __restrict__ psqIn,
        const float* __restrict__ bng, const float* __restrict__ bnb,
        u16* __restrict__ out, float* __restrict__ psumOut, float* __restrict__ psqOut) {
    constexpr int STR = 136;                  // 4 pad | 128 | 4 pad
    __shared__ float tile[36 * STR];
    __shared__ float ss[256], sq[256];

    int blk = ((blockIdx.x & 7) << 8) | (blockIdx.x >> 3);  // XCD chunk swizzle
    int q   = blk & 3;
    int bc  = blk >> 2;
    int c   = bc & 63;
    int r0  = q * 32;
    int tid = threadIdx.x;
    const u16* ip = in + (size_t)bc * NHW;

    float scale = 0.f, shift = 0.f;
    if (BNIN) {
        float s = 0.f, qv = 0.f;
        #pragma unroll
        for (int i = 0; i < 32; ++i) {
            int bb = i >> 2, j = i & 3;
            int idx = ((bb * 64 + c) << 2) + j;
            s += psumIn[idx]; qv += psqIn[idx];
        }
        const float inv = 1.f / (float)(NB * NHW);
        float m = s * inv;
        float var = qv * inv - m * m;
        float rs = rsqrtf(var + EPS);
        scale = rs * bng[c];
        shift = bnb[c] - m * scale;
    }

    #pragma unroll 1
    for (int idx = tid; idx < 36 * 16; idx += 256) {
        int lr = idx >> 4, u = idx & 15;
        int gr = r0 - 2 + lr;
        float v[8] = {0.f, 0.f, 0.f, 0.f, 0.f, 0.f, 0.f, 0.f};
        if (gr >= 0 && gr < NH) {
            u16x8 raw = *(const u16x8*)(ip + gr * NW + u * 8);
            #pragma unroll
            for (int j = 0; j < 8; ++j) {
                float f = bf2f(raw[j]);
                if (BNIN) f = fmaxf(f * scale + shift, 0.f);
                v[j] = f;
            }
        }
        *(float4*)&tile[lr * STR + 4 + u * 8]     = make_float4(v[0], v[1], v[2], v[3]);
        *(float4*)&tile[lr * STR + 4 + u * 8 + 4] = make_float4(v[4], v[5], v[6], v[7]);
        if (u == 0)  *(float4*)&tile[lr * STR]       = make_float4(0.f, 0.f, 0.f, 0.f);
        if (u == 15) *(float4*)&tile[lr * STR + 132] = make_float4(0.f, 0.f, 0.f, 0.f);
    }
    __syncthreads();

    float wc[9];
    #pragma unroll
    for (int k = 0; k < 9; ++k) wc[k] = wgt[c * 9 + k];

    int row  = tid >> 3;
    int col0 = (tid & 7) * 16;
    float o[16];
    float bb = HASBIAS ? bias[c] : 0.f;
    #pragma unroll
    for (int j = 0; j < 16; ++j) o[j] = bb;

    #pragma unroll
    for (int i = 0; i < 3; ++i) {
        const float* rp = &tile[(row + 2 + (i - 1) * DIL) * STR + 4 + col0];
        float4 A  = *(const float4*)(rp - 4);
        float4 B0 = *(const float4*)(rp);
        float4 B1 = *(const float4*)(rp + 4);
        float4 B2 = *(const float4*)(rp + 8);
        float4 B3 = *(const float4*)(rp + 12);
        float4 Cc = *(const float4*)(rp + 16);
        float ww[24] = {A.x,A.y,A.z,A.w, B0.x,B0.y,B0.z,B0.w, B1.x,B1.y,B1.z,B1.w,
                        B2.x,B2.y,B2.z,B2.w, B3.x,B3.y,B3.z,B3.w, Cc.x,Cc.y,Cc.z,Cc.w};
        float w0 = wc[3 * i], w1 = wc[3 * i + 1], w2 = wc[3 * i + 2];
        #pragma unroll
        for (int j = 0; j < 16; ++j)
            o[j] += w0 * ww[4 + j - DIL] + w1 * ww[4 + j] + w2 * ww[4 + j + DIL];
    }

    u16* op = out + (size_t)bc * NHW + (r0 + row) * NW + col0;
    u16x8 o1, o2;
    #pragma unroll
    for (int j = 0; j < 8; ++j) { o1[j] = (u16)f2bf(o[j]); o2[j] = (u16)f2bf(o[8 + j]); }
    *(u16x8*)(op)     = o1;
    *(u16x8*)(op + 8) = o2;

    float s = 0.f, qq = 0.f;
    #pragma unroll
    for (int j = 0; j < 16; ++j) { s += o[j]; qq += o[j] * o[j]; }
    ss[tid] = s; sq[tid] = qq; __syncthreads();
    for (int off = 128; off > 0; off >>= 1) {
        if (tid < off) { ss[tid] += ss[tid + off]; sq[tid] += sq[tid + off]; }
        __syncthreads();
    }
    if (tid == 0) { psumOut[blk] = ss[0]; psqOut[blk] = sq[0]; }
}

// ---------------------------------------------------------------------------
// out = 4*x2*y3*(1+e); SE-MLP folded in (block-uniform (b,c)); svec prescaled.
__global__ void k_final8(const u16* __restrict__ x2, const u16* __restrict__ y3,
                         const float* __restrict__ svec,
                         const float* __restrict__ w1, const float* __restrict__ b1,
                         const float* __restrict__ w2, const float* __restrict__ b2,
                         float* __restrict__ out) {
    __shared__ float sh[64], e1[8], ev[1];
    int tid = threadIdx.x;
    int bc = blockIdx.x >> 3;            // block covers 2048 elems = 1/8 plane
    int b  = bc >> 6, c = bc & 63;

    if (tid < 64) sh[tid] = svec[b * 64 + tid];
    __syncthreads();
    if (tid < 8) {
        float a = b1[tid];
        for (int cc = 0; cc < 64; ++cc) a += sh[cc] * w1[tid * 64 + cc];
        e1[tid] = a > 0.f ? a : 0.f;
    }
    __syncthreads();
    if (tid == 0) {
        float a = b2[c];
        #pragma unroll
        for (int j = 0; j < 8; ++j) a += e1[j] * w2[c * 8 + j];
        ev[0] = 1.f / (1.f + expf(-a));
    }
    __syncthreads();

    int t = blockIdx.x * 256 + tid;      // over SZ/8
    float f = 4.f * (1.f + ev[0]);
    u16x8 av = *(const u16x8*)(x2 + (size_t)t * 8);
    u16x8 bv = *(const u16x8*)(y3 + (size_t)t * 8);
    float4 o0, o1;
    o0.x = f * bf2f(av[0]) * bf2f(bv[0]); o0.y = f * bf2f(av[1]) * bf2f(bv[1]);
    o0.z = f * bf2f(av[2]) * bf2f(bv[2]); o0.w = f * bf2f(av[3]) * bf2f(bv[3]);
    o1.x = f * bf2f(av[4]) * bf2f(bv[4]); o1.y = f * bf2f(av[5]) * bf2f(bv[5]);
    o1.z = f * bf2f(av[6]) * bf2f(bv[6]); o1.w = f * bf2f(av[7]) * bf2f(bv[7]);
    *(float4*)(out + (size_t)t * 8)     = o0;
    *(float4*)(out + (size_t)t * 8 + 4) = o1;
}

// ---------------------------------------------------------------------------
extern "C" void kernel_launch(void* const* d_in, const int* in_sizes, int n_in,
                              void* d_out, int out_size, void* d_ws, size_t ws_size,
                              hipStream_t stream) {
    const float* x     = (const float*)d_in[0];
    const float* fc1w  = (const float*)d_in[1];
    const float* fc1b  = (const float*)d_in[2];
    const float* fc2w  = (const float*)d_in[3];
    const float* fc2b  = (const float*)d_in[4];
    const float* fc3w  = (const float*)d_in[5];
    const float* fc3b  = (const float*)d_in[6];
    const float* fc4w  = (const float*)d_in[7];
    const float* fc4b  = (const float*)d_in[8];
    const float* fc5w  = (const float*)d_in[9];
    const float* fc5b  = (const float*)d_in[10];
    const float* lng   = (const float*)d_in[11];
    const float* lnb   = (const float*)d_in[12];
    const float* pcw   = (const float*)d_in[13];
    const float* dww   = (const float*)d_in[14];
    const float* dwb   = (const float*)d_in[15];
    const float* dwbng = (const float*)d_in[16];
    const float* dwbnb = (const float*)d_in[17];
    const float* ddw   = (const float*)d_in[18];
    const float* ddbng = (const float*)d_in[19];
    const float* ddbnb = (const float*)d_in[20];
    const float* sew1  = (const float*)d_in[21];
    const float* seb1  = (const float*)d_in[22];
    const float* sew2  = (const float*)d_in[23];
    const float* seb2  = (const float*)d_in[24];

    float* out = (float*)d_out;
    u16* wsu = (u16*)d_ws;
    u16* bufA = wsu;                     // xn -> x2
    u16* bufB = wsu + (size_t)SZ;        // t1 -> d1
    u16* bufC = wsu + (size_t)2 * SZ;    // t2 -> d2
    u16* bufD = wsu + (size_t)3 * SZ;    // x1 -> y3
    float* st = (float*)(wsu + (size_t)4 * SZ);
    float* psumA = st;           // 2048
    float* psqA  = st + 2048;    // 2048
    float* psumB = st + 4096;    // 2048
    float* psqB  = st + 6144;    // 2048
    float* svec  = st + 8192;    // 512
    float* pqv   = st + 8704;    // 128
    float* gpart = st + 8832;    // 65536 (1024 blocks x 64 ch)

    dim3 blk(256);
    dim3 blk512(512);
    const float* nil = nullptr;
    const u16*   nilu = nullptr;
    float*       nilf = nullptr;

    // xn = transpose(x) -> bf16 ; block 2048 computes P/Q
    k_transpose<<<2049, blk, 0, stream>>>(x, bufA, fc5w, lng, lnb, pqv);
    // t1,t2 = gelu(fc1(roll_h xn)), gelu(fc3(roll_w- xn))
    k_mfc2<<<NPOS / 128, blk512, 0, stream>>>(bufA, fc1w, fc1b, fc3w, fc3b, bufB, bufC);
    // x1 = fused fc2+fc4+LN+fc5 (+xn residuals)  [fully swapped]
    k_ffuse<<<NPOS / 128, blk512, 0, stream>>>(bufB, bufC, bufA, fc2w, fc2b, fc4w, fc4b,
                                               fc5w, lng, pqv, fc5b, bufD);
    // x2 = pc(x1)
    k_mfc<false, false><<<NPOS / 128, blk512, 0, stream>>>(bufD, pcw, nil, nil, nil, nil, nilu, nilf, bufA);
    // d1 = dwconv3x3(x2, dil=1) + dw_b   [stats -> psumA]
    k_dwlds<1, true, false><<<2048, blk, 0, stream>>>(bufA, dww, dwb, nil, nil, nil, nil, bufB, psumA, psqA);
    // d2 = dwconv3x3(relu(bn1(d1)), dil=2)   [bn1 inline; stats -> psumB]
    k_dwlds<2, false, true><<<2048, blk, 0, stream>>>(bufB, ddw, nil, psumA, psqA, dwbng, dwbnb, bufC, psumB, psqB);
    // y3 = pc(relu(bn2(d2)))   [bn2 inline; SE partials fused]
    k_mfc<true, true><<<NPOS / 128, blk512, 0, stream>>>(bufC, pcw, psumB, psqB, ddbng, ddbnb, bufA, gpart, bufD);
    // SE finalize + final: out = 4*x2*y3*(1+e)
    k_se_fin<<<NB, 64, 0, stream>>>(gpart, svec);
    k_final8<<<SZ / 2048, blk, 0, stream>>>(bufA, bufD, svec, sew1, seb1, sew2, seb2, out);
}

// Round 17
// 138.017 us; speedup vs baseline: 1.3377x; 1.0062x over previous
//
#include <hip/hip_runtime.h>

// Problem constants (fixed by the reference)
constexpr int NB  = 8;
constexpr int NC  = 64;
constexpr int NH  = 128;
constexpr int NW  = 128;
constexpr int NHW = NH * NW;          // 16384
constexpr int CHW = NC * NHW;         // 1048576
constexpr int SZ  = NB * CHW;         // 8388608 elements per tensor
constexpr int NPOS = NB * NHW;        // 131072 spatial positions
constexpr float EPS = 1e-5f;

typedef unsigned short u16;
using bf8   = __attribute__((ext_vector_type(8))) short;   // 8 bf16 = 4 VGPR
using u16x8 = __attribute__((ext_vector_type(8))) u16;
using u16x4 = __attribute__((ext_vector_type(4))) u16;
using f32x4 = __attribute__((ext_vector_type(4))) float;

static __device__ inline short f2bf(float f) {
    union { float f; unsigned int u; } v; v.f = f;
    unsigned int r = v.u + 0x7fffu + ((v.u >> 16) & 1u);   // RNE
    return (short)(r >> 16);
}
static __device__ inline float bf2f(u16 u) {
    union { unsigned int i; float f; } v; v.i = ((unsigned int)u) << 16;
    return v.f;
}

// ---------------------------------------------------------------------------
// (B,N,C) fp32 -> (B,C,H,W) bf16 transpose, LDS-tiled.
// Block 2048 computes the folded-LN P/Q vectors instead (merged k_pq).
__global__ void k_transpose(const float* __restrict__ x, u16* __restrict__ xn,
                            const float* __restrict__ w5, const float* __restrict__ lng,
                            const float* __restrict__ lnb, float* __restrict__ PQ) {
    if (blockIdx.x == 2048) {
        int d = threadIdx.x;
        if (d < 64) {
            float P = 0.f, Q = 0.f;
            for (int c = 0; c < 128; ++c) {
                float wv = w5[c * 64 + d];
                P += lng[c] * wv;
                Q += lnb[c] * wv;
            }
            PQ[d] = P; PQ[64 + d] = Q;
        }
        return;
    }
    __shared__ float t[64 * 65];
    int b   = blockIdx.x >> 8;
    int hw0 = (blockIdx.x & 255) << 6;
    int tid = threadIdx.x;
    #pragma unroll
    for (int k = 0; k < 16; ++k) {
        int idx = tid + (k << 8);
        int c = idx & 63, hwl = idx >> 6;
        t[c * 65 + hwl] = x[((size_t)b * NHW + hw0 + hwl) * NC + c];
    }
    __syncthreads();
    #pragma unroll
    for (int k = 0; k < 16; ++k) {
        int idx = tid + (k << 8);
        int hwl = idx & 63, c = idx >> 6;
        xn[(size_t)(b * NC + c) * NHW + hw0 + hwl] = (u16)f2bf(t[c * 65 + hwl]);
    }
}

// ---------------------------------------------------------------------------
// DUAL channel-linear, swapped operands (D[pos][d], u16x4 stores).
__global__ __launch_bounds__(512) void
k_mfc2(const u16* __restrict__ xn,
       const float* __restrict__ w1, const float* __restrict__ b1,
       const float* __restrict__ w3, const float* __restrict__ b3,
       u16* __restrict__ t1, u16* __restrict__ t2) {
    __shared__ short wA[64 * 64];
    __shared__ short wB[64 * 64];
    int tid = threadIdx.x;
    int l = tid & 63, wv = tid >> 6;
    int q = l >> 4, col = l & 15;
    int bid = ((blockIdx.x & 7) << 7) | (blockIdx.x >> 3);

    {
        const float* wsrc = (wv < 4) ? w1 : w3;
        short* wdst = (wv < 4) ? wA : wB;
        int wv4 = wv & 3;
        #pragma unroll
        for (int i = 0; i < 8; ++i) {
            int c0 = wv4 * 2 + i * 8;
            unsigned int pk = (unsigned int)(u16)f2bf(wsrc[c0 * 64 + l]) |
                              ((unsigned int)(u16)f2bf(wsrc[(c0 + 1) * 64 + l]) << 16);
            *(unsigned int*)&wdst[l * 64 + (c0 ^ ((l & 7) << 3))] = pk;
        }
    }
    __syncthreads();

    int p  = bid * 128 + wv * 16 + col;
    int b  = p >> 14;
    int hw = p & (NHW - 1);
    int h  = hw >> 7, w = hw & 127;
    const u16* inb = xn + (size_t)b * CHW;

    f32x4 acc1[4], acc2[4];
    #pragma unroll
    for (int dt = 0; dt < 4; ++dt) {
        acc1[dt] = (f32x4){0.f, 0.f, 0.f, 0.f};
        acc2[dt] = (f32x4){0.f, 0.f, 0.f, 0.f};
    }
    #pragma unroll
    for (int ks = 0; ks < 2; ++ks) {
        bf8 f1, f2;
        #pragma unroll
        for (int j = 0; j < 8; ++j) {
            int c = ks * 32 + q * 8 + j;
            f1[j] = (short)inb[c * NHW + (((h - c) & 127) << 7) + w];
            f2[j] = (short)inb[c * NHW + (h << 7) + ((w + c) & 127)];
        }
        #pragma unroll
        for (int dt = 0; dt < 4; ++dt) {
            int d = dt * 16 + col;
            int wo = (ks * 32 + q * 8) ^ ((d & 7) << 3);
            acc1[dt] = __builtin_amdgcn_mfma_f32_16x16x32_bf16(f1, *(bf8*)&wA[d * 64 + wo], acc1[dt], 0, 0, 0);
            acc2[dt] = __builtin_amdgcn_mfma_f32_16x16x32_bf16(f2, *(bf8*)&wB[d * 64 + wo], acc2[dt], 0, 0, 0);
        }
    }

    int hwst = (bid * 128 + wv * 16 + q * 4) & (NHW - 1);
    size_t ob = (size_t)b * CHW + hwst;
    #pragma unroll
    for (int dt = 0; dt < 4; ++dt) {
        int d = dt * 16 + col;
        float bb1 = b1[d], bb3 = b3[d];
        u16x4 o1v, o2v;
        #pragma unroll
        for (int r = 0; r < 4; ++r) {
            float v1 = acc1[dt][r] + bb1;
            v1 = 0.5f * v1 * (1.f + erff(v1 * 0.70710678118654752f));
            float v2 = acc2[dt][r] + bb3;
            v2 = 0.5f * v2 * (1.f + erff(v2 * 0.70710678118654752f));
            o1v[r] = (u16)f2bf(v1);
            o2v[r] = (u16)f2bf(v2);
        }
        *(u16x4*)&t1[ob + (size_t)d * NHW] = o1v;
        *(u16x4*)&t2[ob + (size_t)d * NHW] = o2v;
    }
}

// ---------------------------------------------------------------------------
// FUSED fc2 + fc4 + LayerNorm + fc5 (+xn residuals), fully swapped.
__global__ __launch_bounds__(512) void
k_ffuse(const u16* __restrict__ t1, const u16* __restrict__ t2,
        const u16* __restrict__ xnb,
        const float* __restrict__ fc2w, const float* __restrict__ fc2b,
        const float* __restrict__ fc4w, const float* __restrict__ fc4b,
        const float* __restrict__ w5, const float* __restrict__ lng,
        const float* __restrict__ PQ, const float* __restrict__ b5,
        u16* __restrict__ x1out) {
    __shared__ short wA[64 * 64];
    __shared__ short wB[64 * 64];
    __shared__ short wG[64 * 128];
    __shared__ short xt[128 * 140];

    int tid = threadIdx.x;
    int l = tid & 63, wv = tid >> 6;
    int q = l >> 4, col = l & 15;
    int bid = ((blockIdx.x & 7) << 7) | (blockIdx.x >> 3);

    {
        const float* wsrc = (wv < 4) ? fc2w : fc4w;
        short* wdst = (wv < 4) ? wA : wB;
        int wv4 = wv & 3;
        #pragma unroll
        for (int i = 0; i < 8; ++i) {
            int c0 = wv4 * 2 + i * 8;
            unsigned int pk = (unsigned int)(u16)f2bf(wsrc[c0 * 64 + l]) |
                              ((unsigned int)(u16)f2bf(wsrc[(c0 + 1) * 64 + l]) << 16);
            *(unsigned int*)&wdst[l * 64 + (c0 ^ ((l & 7) << 3))] = pk;
        }
    }
    #pragma unroll
    for (int i = 0; i < 8; ++i) {
        int c0 = wv * 2 + i * 16;
        unsigned int pk = (unsigned int)(u16)f2bf(lng[c0] * w5[c0 * 64 + l]) |
                          ((unsigned int)(u16)f2bf(lng[c0 + 1] * w5[(c0 + 1) * 64 + l]) << 16);
        *(unsigned int*)&wG[l * 128 + (c0 ^ ((l & 7) << 3))] = pk;
    }
    __syncthreads();

    int p  = bid * 128 + wv * 16 + col;
    int b  = p >> 14;
    int hw = p & (NHW - 1);
    int h  = hw >> 7, w = hw & 127;
    size_t base = (size_t)b * CHW;

    f32x4 acc1[4], acc2[4];
    #pragma unroll
    for (int dt = 0; dt < 4; ++dt) {
        acc1[dt] = (f32x4){0.f, 0.f, 0.f, 0.f};
        acc2[dt] = (f32x4){0.f, 0.f, 0.f, 0.f};
    }
    #pragma unroll
    for (int ks = 0; ks < 2; ++ks) {
        bf8 f1, f2;
        #pragma unroll
        for (int j = 0; j < 8; ++j) {
            int c = ks * 32 + q * 8 + j;
            f1[j] = (short)t1[base + c * NHW + (h << 7) + ((w - c) & 127)];
            f2[j] = (short)t2[base + c * NHW + (((h - c) & 127) << 7) + w];
        }
        #pragma unroll
        for (int dt = 0; dt < 4; ++dt) {
            int d = dt * 16 + col;
            int wo = (ks * 32 + q * 8) ^ ((d & 7) << 3);
            acc1[dt] = __builtin_amdgcn_mfma_f32_16x16x32_bf16(f1, *(bf8*)&wA[d * 64 + wo], acc1[dt], 0, 0, 0);
            acc2[dt] = __builtin_amdgcn_mfma_f32_16x16x32_bf16(f2, *(bf8*)&wB[d * 64 + wo], acc2[dt], 0, 0, 0);
        }
    }

    int hwst = (bid * 128 + wv * 16 + q * 4) & (NHW - 1);
    size_t ob = base + hwst;
    u16x4 xr4[4];
    #pragma unroll
    for (int dt = 0; dt < 4; ++dt)
        xr4[dt] = *(const u16x4*)&xnb[ob + (size_t)(dt * 16 + col) * NHW];

    float s[4] = {0.f, 0.f, 0.f, 0.f}, sq[4] = {0.f, 0.f, 0.f, 0.f};
    int posr = wv * 16 + q * 4;
    #pragma unroll
    for (int dt = 0; dt < 4; ++dt) {
        int d = dt * 16 + col;
        float bb2 = fc2b[d], bb4 = fc4b[d];
        #pragma unroll
        for (int r = 0; r < 4; ++r) {
            float xv = bf2f(xr4[dt][r]);
            float v1 = acc1[dt][r] + bb2 + xv;
            float v2 = acc2[dt][r] + bb4 + xv;
            s[r]  += v1 + v2;
            sq[r] += v1 * v1 + v2 * v2;
            xt[(posr + r) * 140 + d]      = f2bf(v1);
            xt[(posr + r) * 140 + 64 + d] = f2bf(v2);
        }
    }
    #pragma unroll
    for (int off = 1; off < 16; off <<= 1) {
        #pragma unroll
        for (int r = 0; r < 4; ++r) {
            s[r]  += __shfl_xor(s[r], off);
            sq[r] += __shfl_xor(sq[r], off);
        }
    }
    float rstd[4], mr[4];
    #pragma unroll
    for (int r = 0; r < 4; ++r) {
        float m   = s[r] * (1.f / 128.f);
        float var = sq[r] * (1.f / 128.f) - m * m;
        rstd[r] = rsqrtf(var + EPS);
        mr[r]   = m * rstd[r];
    }
    __syncthreads();

    f32x4 acc[4];
    #pragma unroll
    for (int dt = 0; dt < 4; ++dt) acc[dt] = (f32x4){0.f, 0.f, 0.f, 0.f};
    #pragma unroll
    for (int ks = 0; ks < 4; ++ks) {
        bf8 bfr = *(bf8*)&xt[(wv * 16 + col) * 140 + ks * 32 + q * 8];
        #pragma unroll
        for (int dt = 0; dt < 4; ++dt) {
            int d = dt * 16 + col;
            bf8 wfr = *(bf8*)&wG[d * 128 + ((ks * 32 + q * 8) ^ ((d & 7) << 3))];
            acc[dt] = __builtin_amdgcn_mfma_f32_16x16x32_bf16(bfr, wfr, acc[dt], 0, 0, 0);
        }
    }

    #pragma unroll
    for (int dt = 0; dt < 4; ++dt) {
        int d = dt * 16 + col;
        float pqd = PQ[d], pqq = PQ[64 + d], b5d = b5[d];
        u16x4 ov;
        #pragma unroll
        for (int r = 0; r < 4; ++r) {
            float val = rstd[r] * acc[dt][r] + pqq - mr[r] * pqd + b5d + bf2f(xr4[dt][r]);
            ov[r] = (u16)f2bf(val);
        }
        *(u16x4*)&x1out[ob + (size_t)d * NHW] = ov;
    }
}

// ---------------------------------------------------------------------------
// MFMA pointwise conv (K=64), swapped -> u16x4 stores. 512 threads.
// SEPART: fold SE reduction and store x7 = 4*x2*y3 (bf16) instead of y3.
template<bool BNRELU_IN, bool SEPART>
__global__ __launch_bounds__(512) void
k_mfc(const u16* __restrict__ in, const float* __restrict__ wgt,
      const float* __restrict__ psum, const float* __restrict__ psq,
      const float* __restrict__ bng, const float* __restrict__ bnb,
      const u16* __restrict__ x2in, float* __restrict__ gpart,
      u16* __restrict__ out) {
    __shared__ short wt[64 * 64];
    __shared__ float scl[64], sft[64];
    __shared__ float spart[8][64];
    int tid = threadIdx.x;
    int l = tid & 63, wv = tid >> 6;
    int q = l >> 4, col = l & 15;
    int bid = ((blockIdx.x & 7) << 7) | (blockIdx.x >> 3);

    #pragma unroll
    for (int i = 0; i < 8; ++i) {
        int d = wv * 8 + i;
        wt[d * 64 + (l ^ ((d & 7) << 3))] = f2bf(wgt[d * 64 + l]);
    }
    if (BNRELU_IN && tid < 64) {
        float s = 0.f, qv = 0.f;
        #pragma unroll
        for (int i = 0; i < 32; ++i) {
            int bb = i >> 2, j = i & 3;
            int idx = ((bb * 64 + tid) << 2) + j;
            s += psum[idx]; qv += psq[idx];
        }
        const float inv = 1.f / (float)(NB * NHW);
        float m = s * inv;
        float var = qv * inv - m * m;
        float rs = rsqrtf(var + EPS);
        float sc = rs * bng[tid];
        scl[tid] = sc;
        sft[tid] = bnb[tid] - m * sc;
    }
    __syncthreads();

    int p  = bid * 128 + wv * 16 + col;
    int b  = p >> 14;
    int hw = p & (NHW - 1);
    const u16* inb = in + (size_t)b * CHW;

    f32x4 acc[4];
    #pragma unroll
    for (int dt = 0; dt < 4; ++dt) acc[dt] = (f32x4){0.f, 0.f, 0.f, 0.f};

    #pragma unroll
    for (int ks = 0; ks < 2; ++ks) {
        bf8 bfr;
        #pragma unroll
        for (int j = 0; j < 8; ++j) {
            int c = ks * 32 + q * 8 + j;
            u16 raw = inb[c * NHW + hw];
            if (BNRELU_IN) {
                float v = fmaxf(bf2f(raw) * scl[c] + sft[c], 0.f);
                bfr[j] = f2bf(v);
            } else {
                bfr[j] = (short)raw;
            }
        }
        #pragma unroll
        for (int dt = 0; dt < 4; ++dt) {
            int d = dt * 16 + col;
            bf8 afr = *(bf8*)&wt[d * 64 + ((ks * 32 + q * 8) ^ ((d & 7) << 3))];
            acc[dt] = __builtin_amdgcn_mfma_f32_16x16x32_bf16(bfr, afr, acc[dt], 0, 0, 0);
        }
    }

    int hwst = (bid * 128 + wv * 16 + q * 4) & (NHW - 1);
    size_t ob = (size_t)b * CHW + hwst;
    float pp[4] = {0.f, 0.f, 0.f, 0.f};
    #pragma unroll
    for (int dt = 0; dt < 4; ++dt) {
        int d = dt * 16 + col;
        u16x4 ov;
        if (SEPART) {
            u16x4 xv = *(const u16x4*)&x2in[ob + (size_t)d * NHW];
            #pragma unroll
            for (int r = 0; r < 4; ++r) {
                float x2v = bf2f(xv[r]);
                float y3v = acc[dt][r];
                pp[dt] += x2v * y3v;
                ov[r] = (u16)f2bf(4.f * x2v * y3v);   // x7
            }
        } else {
            #pragma unroll
            for (int r = 0; r < 4; ++r) ov[r] = (u16)f2bf(acc[dt][r]);
        }
        *(u16x4*)&out[ob + (size_t)d * NHW] = ov;
    }

    if (SEPART) {
        #pragma unroll
        for (int dt = 0; dt < 4; ++dt) {
            pp[dt] += __shfl_xor(pp[dt], 16);
            pp[dt] += __shfl_xor(pp[dt], 32);
        }
        if (l < 16) {
            #pragma unroll
            for (int dt = 0; dt < 4; ++dt) spart[wv][dt * 16 + l] = pp[dt];
        }
        __syncthreads();
        if (tid < 64) {
            float s = 0.f;
            #pragma unroll
            for (int w8 = 0; w8 < 8; ++w8) s += spart[w8][tid];
            gpart[(size_t)bid * 64 + tid] = s;
        }
    }
}

// ---------------------------------------------------------------------------
// svec[b*64+c] = (4/NHW) * sum over the b's 128 block-partials
__global__ void k_se_fin(const float* __restrict__ gpart, float* __restrict__ svec) {
    int b = blockIdx.x, c = threadIdx.x;
    float s = 0.f;
    for (int k = 0; k < 128; ++k) s += gpart[(size_t)(b * 128 + k) * 64 + c];
    svec[b * 64 + c] = s * (4.f / (float)NHW);
}

// ---------------------------------------------------------------------------
// Depthwise 3x3 conv dil=1, LDS-tiled; STORE=false -> stats-only (BN pass 1).
template<bool STORE>
__global__ __launch_bounds__(256) void
k_dwlds1(const u16* __restrict__ in, const float* __restrict__ wgt,
         const float* __restrict__ bias,
         u16* __restrict__ out, float* __restrict__ psumOut, float* __restrict__ psqOut) {
    constexpr int STR = 136;
    __shared__ float tile[36 * STR];
    __shared__ float ss[256], sq[256];

    int blk = ((blockIdx.x & 7) << 8) | (blockIdx.x >> 3);
    int q   = blk & 3;
    int bc  = blk >> 2;
    int c   = bc & 63;
    int r0  = q * 32;
    int tid = threadIdx.x;
    const u16* ip = in + (size_t)bc * NHW;

    #pragma unroll 1
    for (int idx = tid; idx < 36 * 16; idx += 256) {
        int lr = idx >> 4, u = idx & 15;
        int gr = r0 - 2 + lr;
        float v[8] = {0.f, 0.f, 0.f, 0.f, 0.f, 0.f, 0.f, 0.f};
        if (gr >= 0 && gr < NH) {
            u16x8 raw = *(const u16x8*)(ip + gr * NW + u * 8);
            #pragma unroll
            for (int j = 0; j < 8; ++j) v[j] = bf2f(raw[j]);
        }
        *(float4*)&tile[lr * STR + 4 + u * 8]     = make_float4(v[0], v[1], v[2], v[3]);
        *(float4*)&tile[lr * STR + 4 + u * 8 + 4] = make_float4(v[4], v[5], v[6], v[7]);
        if (u == 0)  *(float4*)&tile[lr * STR]       = make_float4(0.f, 0.f, 0.f, 0.f);
        if (u == 15) *(float4*)&tile[lr * STR + 132] = make_float4(0.f, 0.f, 0.f, 0.f);
    }
    __syncthreads();

    float wc[9];
    #pragma unroll
    for (int k = 0; k < 9; ++k) wc[k] = wgt[c * 9 + k];

    int row  = tid >> 3;
    int col0 = (tid & 7) * 16;
    float o[16];
    float bb = bias[c];
    #pragma unroll
    for (int j = 0; j < 16; ++j) o[j] = bb;

    #pragma unroll
    for (int i = 0; i < 3; ++i) {
        const float* rp = &tile[(row + 2 + (i - 1)) * STR + 4 + col0];
        float4 A  = *(const float4*)(rp - 4);
        float4 B0 = *(const float4*)(rp);
        float4 B1 = *(const float4*)(rp + 4);
        float4 B2 = *(const float4*)(rp + 8);
        float4 B3 = *(const float4*)(rp + 12);
        float4 Cc = *(const float4*)(rp + 16);
        float ww[24] = {A.x,A.y,A.z,A.w, B0.x,B0.y,B0.z,B0.w, B1.x,B1.y,B1.z,B1.w,
                        B2.x,B2.y,B2.z,B2.w, B3.x,B3.y,B3.z,B3.w, Cc.x,Cc.y,Cc.z,Cc.w};
        float w0 = wc[3 * i], w1 = wc[3 * i + 1], w2 = wc[3 * i + 2];
        #pragma unroll
        for (int j = 0; j < 16; ++j)
            o[j] += w0 * ww[4 + j - 1] + w1 * ww[4 + j] + w2 * ww[4 + j + 1];
    }

    if (STORE) {
        u16* op = out + (size_t)bc * NHW + (r0 + row) * NW + col0;
        u16x8 o1, o2;
        #pragma unroll
        for (int j = 0; j < 8; ++j) { o1[j] = (u16)f2bf(o[j]); o2[j] = (u16)f2bf(o[8 + j]); }
        *(u16x8*)(op)     = o1;
        *(u16x8*)(op + 8) = o2;
    }

    float s = 0.f, qq = 0.f;
    #pragma unroll
    for (int j = 0; j < 16; ++j) { s += o[j]; qq += o[j] * o[j]; }
    ss[tid] = s; sq[tid] = qq; __syncthreads();
    for (int off = 128; off > 0; off >>= 1) {
        if (tid < off) { ss[tid] += ss[tid + off]; sq[tid] += sq[tid + off]; }
        __syncthreads();
    }
    if (tid == 0) { psumOut[blk] = ss[0]; psqOut[blk] = sq[0]; }
}

// ---------------------------------------------------------------------------
// FUSED dw1-recompute + bn1 + relu + dw2(dil2): x2 -> d2 directly, d1 in LDS.
// tile1: x2 rows r0-3..r0+34 (38). tile2: y=relu(bn1(conv1(x2)+dwb)) rows
// r0-2..r0+33 (36). Then dil-2 conv on tile2 -> d2 rows r0..r0+31 + stats.
__global__ __launch_bounds__(256) void
k_dwfuse(const u16* __restrict__ x2, const float* __restrict__ dww,
         const float* __restrict__ dwb,
         const float* __restrict__ psumIn, const float* __restrict__ psqIn,
         const float* __restrict__ bng, const float* __restrict__ bnb,
         const float* __restrict__ ddw,
         u16* __restrict__ out, float* __restrict__ psumOut, float* __restrict__ psqOut) {
    constexpr int STR = 136;
    __shared__ float tile1[38 * STR];   // x2 + halo
    __shared__ float tile2[36 * STR];   // y = relu(bn1(d1))
    __shared__ float ss[256], sq[256];

    int blk = ((blockIdx.x & 7) << 8) | (blockIdx.x >> 3);
    int q   = blk & 3;
    int bc  = blk >> 2;
    int c   = bc & 63;
    int r0  = q * 32;
    int tid = threadIdx.x;
    const u16* ip = x2 + (size_t)bc * NHW;

    // bn1 affine from pass-1 partials
    float scale, shift;
    {
        float s = 0.f, qv = 0.f;
        #pragma unroll
        for (int i = 0; i < 32; ++i) {
            int bb = i >> 2, j = i & 3;
            int idx = ((bb * 64 + c) << 2) + j;
            s += psumIn[idx]; qv += psqIn[idx];
        }
        const float inv = 1.f / (float)(NB * NHW);
        float m = s * inv;
        float var = qv * inv - m * m;
        float rs = rsqrtf(var + EPS);
        scale = rs * bng[c];
        shift = bnb[c] - m * scale;
    }

    // stage x2 rows r0-3 .. r0+34
    #pragma unroll 1
    for (int idx = tid; idx < 38 * 16; idx += 256) {
        int lr = idx >> 4, u = idx & 15;
        int gr = r0 - 3 + lr;
        float v[8] = {0.f, 0.f, 0.f, 0.f, 0.f, 0.f, 0.f, 0.f};
        if (gr >= 0 && gr < NH) {
            u16x8 raw = *(const u16x8*)(ip + gr * NW + u * 8);
            #pragma unroll
            for (int j = 0; j < 8; ++j) v[j] = bf2f(raw[j]);
        }
        *(float4*)&tile1[lr * STR + 4 + u * 8]     = make_float4(v[0], v[1], v[2], v[3]);
        *(float4*)&tile1[lr * STR + 4 + u * 8 + 4] = make_float4(v[4], v[5], v[6], v[7]);
        if (u == 0)  *(float4*)&tile1[lr * STR]       = make_float4(0.f, 0.f, 0.f, 0.f);
        if (u == 15) *(float4*)&tile1[lr * STR + 132] = make_float4(0.f, 0.f, 0.f, 0.f);
    }
    __syncthreads();

    float wc1[9], wc2[9];
    #pragma unroll
    for (int k = 0; k < 9; ++k) { wc1[k] = dww[c * 9 + k]; wc2[k] = ddw[c * 9 + k]; }
    float dbias = dwb[c];

    // compute tile2 rows (d1 rows r0-2..r0+33), float4 granularity
    #pragma unroll 1
    for (int idx = tid; idx < 36 * 32; idx += 256) {
        int lr2 = idx >> 5, w4 = idx & 31;
        int gr2 = r0 - 2 + lr2;            // global d1 row
        float o0 = 0.f, o1 = 0.f, o2 = 0.f, o3 = 0.f;
        if (gr2 >= 0 && gr2 < NH) {
            o0 = o1 = o2 = o3 = dbias;
            #pragma unroll
            for (int i = 0; i < 3; ++i) {
                // x2 row gr2-1+i -> tile1 row lr2+i
                const float* rp = &tile1[(lr2 + i) * STR + 4 + w4 * 4];
                float4 A = *(const float4*)(rp - 4);
                float4 M = *(const float4*)(rp);
                float4 R = *(const float4*)(rp + 4);
                float win[12] = {A.x,A.y,A.z,A.w, M.x,M.y,M.z,M.w, R.x,R.y,R.z,R.w};
                float w0 = wc1[3 * i], w1 = wc1[3 * i + 1], w2 = wc1[3 * i + 2];
                o0 += w0 * win[3] + w1 * win[4] + w2 * win[5];
                o1 += w0 * win[4] + w1 * win[5] + w2 * win[6];
                o2 += w0 * win[5] + w1 * win[6] + w2 * win[7];
                o3 += w0 * win[6] + w1 * win[7] + w2 * win[8];
            }
            o0 = fmaxf(o0 * scale + shift, 0.f);
            o1 = fmaxf(o1 * scale + shift, 0.f);
            o2 = fmaxf(o2 * scale + shift, 0.f);
            o3 = fmaxf(o3 * scale + shift, 0.f);
        }
        *(float4*)&tile2[lr2 * STR + 4 + w4 * 4] = make_float4(o0, o1, o2, o3);
        if (w4 == 0)  *(float4*)&tile2[lr2 * STR]       = make_float4(0.f, 0.f, 0.f, 0.f);
        if (w4 == 31) *(float4*)&tile2[lr2 * STR + 132] = make_float4(0.f, 0.f, 0.f, 0.f);
    }
    __syncthreads();

    // dil-2 conv on tile2 -> d2 rows r0..r0+31
    int row  = tid >> 3;
    int col0 = (tid & 7) * 16;
    float o[16];
    #pragma unroll
    for (int j = 0; j < 16; ++j) o[j] = 0.f;

    #pragma unroll
    for (int i = 0; i < 3; ++i) {
        const float* rp = &tile2[(row + 2 + (i - 1) * 2) * STR + 4 + col0];
        float4 A  = *(const float4*)(rp - 4);
        float4 B0 = *(const float4*)(rp);
        float4 B1 = *(const float4*)(rp + 4);
        float4 B2 = *(const float4*)(rp + 8);
        float4 B3 = *(const float4*)(rp + 12);
        float4 Cc = *(const float4*)(rp + 16);
        float ww[24] = {A.x,A.y,A.z,A.w, B0.x,B0.y,B0.z,B0.w, B1.x,B1.y,B1.z,B1.w,
                        B2.x,B2.y,B2.z,B2.w, B3.x,B3.y,B3.z,B3.w, Cc.x,Cc.y,Cc.z,Cc.w};
        float w0 = wc2[3 * i], w1 = wc2[3 * i + 1], w2 = wc2[3 * i + 2];
        #pragma unroll
        for (int j = 0; j < 16; ++j)
            o[j] += w0 * ww[4 + j - 2] + w1 * ww[4 + j] + w2 * ww[4 + j + 2];
    }

    u16* op = out + (size_t)bc * NHW + (r0 + row) * NW + col0;
    u16x8 o1v, o2v;
    #pragma unroll
    for (int j = 0; j < 8; ++j) { o1v[j] = (u16)f2bf(o[j]); o2v[j] = (u16)f2bf(o[8 + j]); }
    *(u16x8*)(op)     = o1v;
    *(u16x8*)(op + 8) = o2v;

    float s = 0.f, qq = 0.f;
    #pragma unroll
    for (int j = 0; j < 16; ++j) { s += o[j]; qq += o[j] * o[j]; }
    ss[tid] = s; sq[tid] = qq; __syncthreads();
    for (int off = 128; off > 0; off >>= 1) {
        if (tid < off) { ss[tid] += ss[tid + off]; sq[tid] += sq[tid + off]; }
        __syncthreads();
    }
    if (tid == 0) { psumOut[blk] = ss[0]; psqOut[blk] = sq[0]; }
}

// ---------------------------------------------------------------------------
// out = x7 * (1 + e); SE-MLP folded in; x7 already includes the factor 4.
__global__ void k_final8(const u16* __restrict__ x7,
                         const float* __restrict__ svec,
                         const float* __restrict__ w1, const float* __restrict__ b1,
                         const float* __restrict__ w2, const float* __restrict__ b2,
                         float* __restrict__ out) {
    __shared__ float sh[64], e1[8], ev[1];
    int tid = threadIdx.x;
    int bc = blockIdx.x >> 3;
    int b  = bc >> 6, c = bc & 63;

    if (tid < 64) sh[tid] = svec[b * 64 + tid];
    __syncthreads();
    if (tid < 8) {
        float a = b1[tid];
        for (int cc = 0; cc < 64; ++cc) a += sh[cc] * w1[tid * 64 + cc];
        e1[tid] = a > 0.f ? a : 0.f;
    }
    __syncthreads();
    if (tid == 0) {
        float a = b2[c];
        #pragma unroll
        for (int j = 0; j < 8; ++j) a += e1[j] * w2[c * 8 + j];
        ev[0] = 1.f / (1.f + expf(-a));
    }
    __syncthreads();

    int t = blockIdx.x * 256 + tid;      // over SZ/8
    float f = 1.f + ev[0];
    u16x8 av = *(const u16x8*)(x7 + (size_t)t * 8);
    float4 o0, o1;
    o0.x = f * bf2f(av[0]); o0.y = f * bf2f(av[1]);
    o0.z = f * bf2f(av[2]); o0.w = f * bf2f(av[3]);
    o1.x = f * bf2f(av[4]); o1.y = f * bf2f(av[5]);
    o1.z = f * bf2f(av[6]); o1.w = f * bf2f(av[7]);
    *(float4*)(out + (size_t)t * 8)     = o0;
    *(float4*)(out + (size_t)t * 8 + 4) = o1;
}

// ---------------------------------------------------------------------------
extern "C" void kernel_launch(void* const* d_in, const int* in_sizes, int n_in,
                              void* d_out, int out_size, void* d_ws, size_t ws_size,
                              hipStream_t stream) {
    const float* x     = (const float*)d_in[0];
    const float* fc1w  = (const float*)d_in[1];
    const float* fc1b  = (const float*)d_in[2];
    const float* fc2w  = (const float*)d_in[3];
    const float* fc2b  = (const float*)d_in[4];
    const float* fc3w  = (const float*)d_in[5];
    const float* fc3b  = (const float*)d_in[6];
    const float* fc4w  = (const float*)d_in[7];
    const float* fc4b  = (const float*)d_in[8];
    const float* fc5w  = (const float*)d_in[9];
    const float* fc5b  = (const float*)d_in[10];
    const float* lng   = (const float*)d_in[11];
    const float* lnb   = (const float*)d_in[12];
    const float* pcw   = (const float*)d_in[13];
    const float* dww   = (const float*)d_in[14];
    const float* dwb   = (const float*)d_in[15];
    const float* dwbng = (const float*)d_in[16];
    const float* dwbnb = (const float*)d_in[17];
    const float* ddw   = (const float*)d_in[18];
    const float* ddbng = (const float*)d_in[19];
    const float* ddbnb = (const float*)d_in[20];
    const float* sew1  = (const float*)d_in[21];
    const float* seb1  = (const float*)d_in[22];
    const float* sew2  = (const float*)d_in[23];
    const float* seb2  = (const float*)d_in[24];

    float* out = (float*)d_out;
    u16* wsu = (u16*)d_ws;
    u16* bufA = wsu;                     // xn -> x2
    u16* bufB = wsu + (size_t)SZ;        // t1
    u16* bufC = wsu + (size_t)2 * SZ;    // t2 -> d2
    u16* bufD = wsu + (size_t)3 * SZ;    // x1 -> x7
    float* st = (float*)(wsu + (size_t)4 * SZ);
    float* psumA = st;           // 2048
    float* psqA  = st + 2048;    // 2048
    float* psumB = st + 4096;    // 2048
    float* psqB  = st + 6144;    // 2048
    float* svec  = st + 8192;    // 512
    float* pqv   = st + 8704;    // 128
    float* gpart = st + 8832;    // 65536

    dim3 blk(256);
    dim3 blk512(512);
    const float* nil = nullptr;
    const u16*   nilu = nullptr;
    float*       nilf = nullptr;
    u16*         nilw = nullptr;

    // xn = transpose(x) -> bf16 ; block 2048 computes P/Q
    k_transpose<<<2049, blk, 0, stream>>>(x, bufA, fc5w, lng, lnb, pqv);
    // t1,t2 = gelu(fc1(roll_h xn)), gelu(fc3(roll_w- xn))
    k_mfc2<<<NPOS / 128, blk512, 0, stream>>>(bufA, fc1w, fc1b, fc3w, fc3b, bufB, bufC);
    // x1 = fused fc2+fc4+LN+fc5 (+xn residuals)
    k_ffuse<<<NPOS / 128, blk512, 0, stream>>>(bufB, bufC, bufA, fc2w, fc2b, fc4w, fc4b,
                                               fc5w, lng, pqv, fc5b, bufD);
    // x2 = pc(x1)
    k_mfc<false, false><<<NPOS / 128, blk512, 0, stream>>>(bufD, pcw, nil, nil, nil, nil, nilu, nilf, bufA);
    // dw1 stats only (no store): bn1 stats -> psumA
    k_dwlds1<false><<<2048, blk, 0, stream>>>(bufA, dww, dwb, nilw, psumA, psqA);
    // d2 = dwconv_dil2(relu(bn1(dwconv_dil1(x2)+dwb)))  [d1 recomputed in LDS]
    k_dwfuse<<<2048, blk, 0, stream>>>(bufA, dww, dwb, psumA, psqA, dwbng, dwbnb,
                                       ddw, bufC, psumB, psqB);
    // x7 = 4*x2*pc(relu(bn2(d2)))  [bn2 inline; SE partials fused]
    k_mfc<true, true><<<NPOS / 128, blk512, 0, stream>>>(bufC, pcw, psumB, psqB, ddbng, ddbnb, bufA, gpart, bufD);
    // SE finalize + final: out = x7*(1+e)
    k_se_fin<<<NB, 64, 0, stream>>>(gpart, svec);
    k_final8<<<SZ / 2048, blk, 0, stream>>>(bufD, svec, sew1, seb1, sew2, seb2, out);
}